// Round 1
// baseline (10779.336 us; speedup 1.0000x reference)
//
#include <hip/hip_runtime.h>
#include <hip/hip_cooperative_groups.h>
#include <cstdint>
#include <cstddef>

namespace cg = cooperative_groups;

typedef __attribute__((ext_vector_type(8))) short short8;   // 8 bf16 (4 VGPRs) MFMA frag
typedef __attribute__((ext_vector_type(4))) float floatx4;  // MFMA accumulator

#define T_STEPS 128
#define BATCH   256
#define IDIM    512
#define HDIM    512
#define KHIST   32

__device__ __forceinline__ unsigned short f2bf(float x) {
  union { float f; unsigned u; } v; v.f = x;
  unsigned r = v.u + 0x7fffu + ((v.u >> 16) & 1u);   // RNE
  return (unsigned short)(r >> 16);
}
__device__ __forceinline__ float bf2f(unsigned short s) {
  union { unsigned u; float f; } v; v.u = ((unsigned)s) << 16; return v.f;
}
__device__ __forceinline__ float sigm(float x) { return 1.0f / (1.0f + __expf(-x)); }
__device__ __forceinline__ float tanh_f(float x) {
  float ax = fabsf(x);
  float e = __expf(-2.0f * ax);
  float t = (1.0f - e) / (1.0f + e);
  return x < 0.0f ? -t : t;
}

// ---------------- prep kernels ----------------

// fp32 -> bf16 cast, 4 elems/thread
__global__ void cast4_kernel(const float* __restrict__ src, unsigned short* __restrict__ dst, int n4) {
  int i = blockIdx.x * blockDim.x + threadIdx.x;
  if (i >= n4) return;
  float4 v = reinterpret_cast<const float4*>(src)[i];
  ushort4 o;
  o.x = f2bf(v.x); o.y = f2bf(v.y); o.z = f2bf(v.z); o.w = f2bf(v.w);
  reinterpret_cast<ushort4*>(dst)[i] = o;
}

// pack [W_ih ; W_hh] along K: W2[n][k] = k<512 ? W_ih[n][k] : W_hh[n][k-512], bf16
__global__ void pack_w2_kernel(const float* __restrict__ Wih, const float* __restrict__ Whh,
                               unsigned short* __restrict__ W2) {
  int i4 = blockIdx.x * blockDim.x + threadIdx.x;   // over 2048*1024/4
  if (i4 >= (2048 * 1024 / 4)) return;
  int i = i4 * 4; int n = i >> 10; int k = i & 1023;
  float4 v = (k < 512) ? reinterpret_cast<const float4*>(Wih + n * 512 + k)[0]
                       : reinterpret_cast<const float4*>(Whh + n * 512 + (k - 512))[0];
  ushort4 o;
  o.x = f2bf(v.x); o.y = f2bf(v.y); o.z = f2bf(v.z); o.w = f2bf(v.w);
  reinterpret_cast<ushort4*>(W2 + i)[0] = o;
}

// wd2[j][h] = c_{j+1}(h) frac-diff coeffs; bA = b_mih+b_mhh; bB = b_ih+b_hh
__global__ void prep_misc_kernel(const float* __restrict__ b_d,
                                 const float* __restrict__ b_mih, const float* __restrict__ b_mhh,
                                 const float* __restrict__ b_ih,  const float* __restrict__ b_hh,
                                 float* __restrict__ wd2, float* __restrict__ bA, float* __restrict__ bB) {
  int tid = threadIdx.x;  // 1024 threads, 1 block
  if (tid < HDIM) {
    float d = 0.5f * sigm(b_d[tid]);
    float c = 1.0f;
    for (int i = 0; i < KHIST; ++i) {
      c *= ((float)i - d) / ((float)i + 1.0f);
      wd2[i * HDIM + tid] = c;          // wd2[j-1] = c_j
    }
  }
  for (int n = tid; n < 3 * HDIM; n += 1024) bA[n] = b_mih[n] + b_mhh[n];
  for (int n = tid; n < 4 * HDIM; n += 1024) bB[n] = b_ih[n] + b_hh[n];
}

// ---------------- big input-projection GEMM ----------------
// GX[m][n] = sum_k Xb[m][k]*Wmih[n][k] + bA[n],  m = t*256+b, (32768 x 1536), K=512
__global__ __launch_bounds__(256) void gx_gemm_kernel(const unsigned short* __restrict__ Xb,
                                                      const unsigned short* __restrict__ Wb,
                                                      const float* __restrict__ bA,
                                                      float* __restrict__ GXf,
                                                      unsigned short* __restrict__ GXh,
                                                      int gxf32) {
  const int lane = threadIdx.x & 63;
  const int wave = threadIdx.x >> 6;
  const int q = lane >> 4, r16 = lane & 15;
  const int m0 = blockIdx.y * 64 + wave * 16;
  const int n0 = blockIdx.x * 64;
  floatx4 acc[4];
  #pragma unroll
  for (int i = 0; i < 4; ++i) acc[i] = (floatx4){0.f, 0.f, 0.f, 0.f};
  const unsigned short* arow = Xb + (size_t)(m0 + r16) * IDIM;
  #pragma unroll 4
  for (int k0 = 0; k0 < IDIM; k0 += 32) {
    short8 a = *(const short8*)(arow + k0 + q * 8);
    #pragma unroll
    for (int nt = 0; nt < 4; ++nt) {
      short8 b = *(const short8*)(Wb + (size_t)(n0 + nt * 16 + r16) * IDIM + k0 + q * 8);
      acc[nt] = __builtin_amdgcn_mfma_f32_16x16x32_bf16(a, b, acc[nt], 0, 0, 0);
    }
  }
  #pragma unroll
  for (int nt = 0; nt < 4; ++nt) {
    int col = n0 + nt * 16 + r16;
    float bias = bA[col];
    #pragma unroll
    for (int j = 0; j < 4; ++j) {
      int row = m0 + q * 4 + j;
      float v = acc[nt][j] + bias;
      if (gxf32) GXf[(size_t)row * 1536 + col] = v;
      else       GXh[(size_t)row * 1536 + col] = f2bf(v);
    }
  }
}

// ---------------- persistent recurrent kernel ----------------
// 256 blocks x 128 threads = 512 waves; wave -> (mt, ht) 16x16 patch covering all gates.
// Double-buffered A2 = [h1 | h2] (256 x 1024 bf16) and c2 (256 x 512 f32); circular hist (f32).
__global__ __launch_bounds__(128) void recurrent_kernel(
    const float* __restrict__ GXf, const unsigned short* __restrict__ GXh, int gxf32,
    const unsigned short* __restrict__ Wmhh,   // (1536 x 512) bf16, N-major
    const unsigned short* __restrict__ W2,     // (2048 x 1024) bf16, N-major
    const float* __restrict__ bB,              // (2048)
    const float* __restrict__ wd2,             // (32 x 512)
    float* __restrict__ hist,                  // (32 x 256 x 512) f32 circular
    unsigned short* __restrict__ A2,           // (2 x 256 x 1024) bf16
    float* __restrict__ c2,                    // (2 x 256 x 512) f32
    float* __restrict__ sel,                   // (256 x 512) f32
    const int* __restrict__ length) {
  cg::grid_group grid = cg::this_grid();
  const int lane = threadIdx.x & 63;
  const int wave = (blockIdx.x << 1) | (threadIdx.x >> 6);  // 0..511
  const int mt = wave & 15;        // 16 m-tiles of 16 rows
  const int ht = wave >> 4;        // 32 h-tiles of 16 cols
  const int q = lane >> 4, r16 = lane & 15;
  const int koff = q * 8;
  const int mrow = mt * 16 + r16;       // A-frag row for loads
  const int hcol = ht * 16 + r16;       // B-frag row (= h col in epilogue)
  const int bbase = mt * 16 + q * 4;    // epilogue rows bbase..bbase+3

  for (int t = 0; t < T_STEPS; ++t) {
    const int w = t & 1, rb = w ^ 1;
    const unsigned short* A2r = A2 + (size_t)rb * (BATCH * 1024);
    unsigned short* A2w = A2 + (size_t)w * (BATCH * 1024);

    // ---- Phase A: g = h1 @ W_mhh^T (+GX) ----
    floatx4 accA[3];
    #pragma unroll
    for (int i = 0; i < 3; ++i) accA[i] = (floatx4){0.f, 0.f, 0.f, 0.f};
    #pragma unroll 4
    for (int k0 = 0; k0 < 512; k0 += 32) {
      short8 a = *(const short8*)(A2r + (size_t)mrow * 1024 + k0 + koff);
      #pragma unroll
      for (int g = 0; g < 3; ++g) {
        short8 b = *(const short8*)(Wmhh + (size_t)(g * 512 + hcol) * 512 + k0 + koff);
        accA[g] = __builtin_amdgcn_mfma_f32_16x16x32_bf16(a, b, accA[g], 0, 0, 0);
      }
    }
    // fused gate + frac-diff filter epilogue
    {
      float f[4] = {0.f, 0.f, 0.f, 0.f};
      #pragma unroll 4
      for (int jj = 1; jj <= KHIST; ++jj) {
        int s = (t - jj) & (KHIST - 1);
        float wc = wd2[(jj - 1) * HDIM + hcol];
        const float* hrow = hist + ((size_t)s * BATCH + bbase) * HDIM + hcol;
        f[0] += wc * hrow[0];
        f[1] += wc * hrow[HDIM];
        f[2] += wc * hrow[2 * HDIM];
        f[3] += wc * hrow[3 * HDIM];
      }
      #pragma unroll
      for (int j = 0; j < 4; ++j) {
        int b = bbase + j;
        size_t gidx = (size_t)(t * BATCH + b) * 1536 + hcol;
        float gI, gO, gG;
        if (gxf32) { gI = GXf[gidx]; gO = GXf[gidx + 512]; gG = GXf[gidx + 1024]; }
        else       { gI = bf2f(GXh[gidx]); gO = bf2f(GXh[gidx + 512]); gG = bf2f(GXh[gidx + 1024]); }
        gI += accA[0][j]; gO += accA[1][j]; gG += accA[2][j];
        float ig = sigm(gI), og = sigm(gO), cand = tanh_f(gG);
        float c1v = ig * cand - f[j];
        hist[((size_t)(t & (KHIST - 1)) * BATCH + b) * HDIM + hcol] = c1v;
        A2w[(size_t)b * 1024 + hcol] = f2bf(og * tanh_f(c1v));   // h1n
      }
    }
    grid.sync();

    // ---- Phase B: g2 = [h1n|h2] @ [W_ih;W_hh]^T ----
    floatx4 accB[4];
    #pragma unroll
    for (int i = 0; i < 4; ++i) accB[i] = (floatx4){0.f, 0.f, 0.f, 0.f};
    #pragma unroll 4
    for (int k0 = 0; k0 < 512; k0 += 32) {       // h1n part (this step, buffer w)
      short8 a = *(const short8*)(A2w + (size_t)mrow * 1024 + k0 + koff);
      #pragma unroll
      for (int g = 0; g < 4; ++g) {
        short8 b = *(const short8*)(W2 + (size_t)(g * 512 + hcol) * 1024 + k0 + koff);
        accB[g] = __builtin_amdgcn_mfma_f32_16x16x32_bf16(a, b, accB[g], 0, 0, 0);
      }
    }
    #pragma unroll 4
    for (int k0 = 512; k0 < 1024; k0 += 32) {    // h2 part (prev step, buffer rb)
      short8 a = *(const short8*)(A2r + (size_t)mrow * 1024 + k0 + koff);
      #pragma unroll
      for (int g = 0; g < 4; ++g) {
        short8 b = *(const short8*)(W2 + (size_t)(g * 512 + hcol) * 1024 + k0 + koff);
        accB[g] = __builtin_amdgcn_mfma_f32_16x16x32_bf16(a, b, accB[g], 0, 0, 0);
      }
    }
    {
      const float* c2r = c2 + (size_t)rb * (BATCH * HDIM);
      float* c2w = c2 + (size_t)w * (BATCH * HDIM);
      #pragma unroll
      for (int j = 0; j < 4; ++j) {
        int b = bbase + j;
        float gi = accB[0][j] + bB[hcol];
        float gf = accB[1][j] + bB[512 + hcol];
        float gg = accB[2][j] + bB[1024 + hcol];
        float go = accB[3][j] + bB[1536 + hcol];
        float c2n = sigm(gf) * c2r[(size_t)b * HDIM + hcol] + sigm(gi) * tanh_f(gg);
        c2w[(size_t)b * HDIM + hcol] = c2n;
        float h2n = tanh_f(sigm(go) * tanh_f(c2n));   // extra tanh as in source
        A2w[(size_t)b * 1024 + 512 + hcol] = f2bf(h2n);
        if (length[b] == t) sel[(size_t)b * HDIM + hcol] = h2n;
      }
    }
    grid.sync();
  }
}

// ---------------- output head: logits + log_softmax ----------------
__global__ void out_head_kernel(const float* __restrict__ sel, const float* __restrict__ Wout,
                                const float* __restrict__ bout, float* __restrict__ out) {
  int b = blockIdx.x, lane = threadIdx.x;   // 256 blocks x 64 threads
  float acc[5] = {0.f, 0.f, 0.f, 0.f, 0.f};
  for (int j = lane; j < HDIM; j += 64) {
    float x = sel[(size_t)b * HDIM + j];
    #pragma unroll
    for (int o = 0; o < 5; ++o) acc[o] += x * Wout[o * HDIM + j];
  }
  #pragma unroll
  for (int o = 0; o < 5; ++o)
    for (int off = 32; off > 0; off >>= 1) acc[o] += __shfl_down(acc[o], off);
  if (lane == 0) {
    float v[5]; float m = -1e30f;
    #pragma unroll
    for (int o = 0; o < 5; ++o) { v[o] = acc[o] + bout[o]; m = fmaxf(m, v[o]); }
    float s = 0.f;
    #pragma unroll
    for (int o = 0; o < 5; ++o) s += __expf(v[o] - m);
    float l = logf(s) + m;
    #pragma unroll
    for (int o = 0; o < 5; ++o) out[b * 5 + o] = v[o] - l;
  }
}

// ---------------- launch ----------------
extern "C" void kernel_launch(void* const* d_in, const int* in_sizes, int n_in,
                              void* d_out, int out_size, void* d_ws, size_t ws_size,
                              hipStream_t stream) {
  const float* x      = (const float*)d_in[0];
  const int*   length = (const int*)d_in[1];
  const float* b_d    = (const float*)d_in[2];
  const float* W_mih  = (const float*)d_in[3];
  const float* W_mhh  = (const float*)d_in[4];
  const float* b_mih  = (const float*)d_in[5];
  const float* b_mhh  = (const float*)d_in[6];
  const float* W_ih   = (const float*)d_in[7];
  const float* W_hh   = (const float*)d_in[8];
  const float* b_ih   = (const float*)d_in[9];
  const float* b_hh   = (const float*)d_in[10];
  const float* W_out  = (const float*)d_in[11];
  const float* b_out  = (const float*)d_in[12];
  float* out = (float*)d_out;

  char* ws = (char*)d_ws;
  size_t off = 0;
  auto take = [&](size_t bytes) -> char* {
    char* p = ws + off;
    off += (bytes + 255) & ~(size_t)255;
    return p;
  };
  const size_t GX_ELEMS = (size_t)T_STEPS * BATCH * 1536;

  unsigned short* Xb     = (unsigned short*)take((size_t)T_STEPS * BATCH * IDIM * 2);  // 33.5MB
  unsigned short* Wmih_b = (unsigned short*)take(1536 * 512 * 2);
  unsigned short* Wmhh_b = (unsigned short*)take(1536 * 512 * 2);
  unsigned short* W2_b   = (unsigned short*)take(2048 * 1024 * 2);
  float* bA  = (float*)take(1536 * 4);
  float* bB  = (float*)take(2048 * 4);
  float* wd2 = (float*)take(KHIST * HDIM * 4);
  const size_t STATE_BYTES = (size_t)KHIST * BATCH * HDIM * 4   // hist f32
                           + (size_t)2 * BATCH * 1024 * 2       // A2 bf16 x2
                           + (size_t)2 * BATCH * HDIM * 4;      // c2 f32 x2
  char* state = take(STATE_BYTES);
  float* hist = (float*)state;
  unsigned short* A2 = (unsigned short*)(state + (size_t)KHIST * BATCH * HDIM * 4);
  float* c2 = (float*)(state + (size_t)KHIST * BATCH * HDIM * 4 + (size_t)2 * BATCH * 1024 * 2);
  float* sel = (float*)take((size_t)BATCH * HDIM * 4);
  size_t base_off = off;

  // GX: fp32 if workspace allows (accuracy), else bf16
  int gxf32 = (base_off + GX_ELEMS * 4 <= ws_size) ? 1 : 0;
  char* gxp = take(GX_ELEMS * (gxf32 ? 4 : 2));
  float* GXf = (float*)gxp;
  unsigned short* GXh = (unsigned short*)gxp;
  if (off > ws_size) return;  // workspace too small -> loud validation failure

  hipMemsetAsync(state, 0, STATE_BYTES, stream);
  prep_misc_kernel<<<1, 1024, 0, stream>>>(b_d, b_mih, b_mhh, b_ih, b_hh, wd2, bA, bB);
  cast4_kernel<<<(T_STEPS * BATCH * IDIM / 4 + 255) / 256, 256, 0, stream>>>(x, Xb, T_STEPS * BATCH * IDIM / 4);
  cast4_kernel<<<(1536 * 512 / 4 + 255) / 256, 256, 0, stream>>>(W_mih, Wmih_b, 1536 * 512 / 4);
  cast4_kernel<<<(1536 * 512 / 4 + 255) / 256, 256, 0, stream>>>(W_mhh, Wmhh_b, 1536 * 512 / 4);
  pack_w2_kernel<<<(2048 * 1024 / 4 + 255) / 256, 256, 0, stream>>>(W_ih, W_hh, W2_b);
  gx_gemm_kernel<<<dim3(1536 / 64, T_STEPS * BATCH / 64), 256, 0, stream>>>(Xb, Wmih_b, bA, GXf, GXh, gxf32);

  void* kargs[] = { (void*)&GXf, (void*)&GXh, (void*)&gxf32, (void*)&Wmhh_b, (void*)&W2_b,
                    (void*)&bB, (void*)&wd2, (void*)&hist, (void*)&A2, (void*)&c2,
                    (void*)&sel, (void*)&length };
  hipLaunchCooperativeKernel((void*)recurrent_kernel, dim3(256), dim3(128), kargs, 0, stream);

  out_head_kernel<<<BATCH, 64, 0, stream>>>(sel, W_out, b_out, out);
}

// Round 2
// 10327.147 us; speedup vs baseline: 1.0438x; 1.0438x over previous
//
#include <hip/hip_runtime.h>
#include <hip/hip_cooperative_groups.h>
#include <cstdint>
#include <cstddef>

typedef __attribute__((ext_vector_type(8))) short short8;   // 8 bf16 (4 VGPRs) MFMA frag
typedef __attribute__((ext_vector_type(4))) float floatx4;  // MFMA accumulator

#define T_STEPS 128
#define BATCH   256
#define IDIM    512
#define HDIM    512
#define KHIST   32
#define D_RING  4

// LDS layout sizes
#define WA_STRIDE 520      // 512 + 8 pad (bank spread)
#define WB_STRIDE 1032     // 1024 + 8 pad
#define LDS_BYTES 148480   // max(WB 64*1032*2 + EX 16384, WA 48*520*2 + HIST 65536)

__device__ __forceinline__ unsigned short f2bf(float x) {
  union { float f; unsigned u; } v; v.f = x;
  unsigned r = v.u + 0x7fffu + ((v.u >> 16) & 1u);   // RNE
  return (unsigned short)(r >> 16);
}
__device__ __forceinline__ float bf2f(unsigned short s) {
  union { unsigned u; float f; } v; v.u = ((unsigned)s) << 16; return v.f;
}
__device__ __forceinline__ float sigm(float x) { return 1.0f / (1.0f + __expf(-x)); }
__device__ __forceinline__ float tanh_f(float x) {
  float ax = fabsf(x);
  float e = __expf(-2.0f * ax);
  float t = (1.0f - e) / (1.0f + e);
  return x < 0.0f ? -t : t;
}

// ---------------- prep kernels ----------------

__global__ void cast4_kernel(const float* __restrict__ src, unsigned short* __restrict__ dst, int n4) {
  int i = blockIdx.x * blockDim.x + threadIdx.x;
  if (i >= n4) return;
  float4 v = reinterpret_cast<const float4*>(src)[i];
  ushort4 o;
  o.x = f2bf(v.x); o.y = f2bf(v.y); o.z = f2bf(v.z); o.w = f2bf(v.w);
  reinterpret_cast<ushort4*>(dst)[i] = o;
}

__global__ void pack_w2_kernel(const float* __restrict__ Wih, const float* __restrict__ Whh,
                               unsigned short* __restrict__ W2) {
  int i4 = blockIdx.x * blockDim.x + threadIdx.x;   // over 2048*1024/4
  if (i4 >= (2048 * 1024 / 4)) return;
  int i = i4 * 4; int n = i >> 10; int k = i & 1023;
  float4 v = (k < 512) ? reinterpret_cast<const float4*>(Wih + n * 512 + k)[0]
                       : reinterpret_cast<const float4*>(Whh + n * 512 + (k - 512))[0];
  ushort4 o;
  o.x = f2bf(v.x); o.y = f2bf(v.y); o.z = f2bf(v.z); o.w = f2bf(v.w);
  reinterpret_cast<ushort4*>(W2 + i)[0] = o;
}

__global__ void prep_misc_kernel(const float* __restrict__ b_d,
                                 const float* __restrict__ b_mih, const float* __restrict__ b_mhh,
                                 const float* __restrict__ b_ih,  const float* __restrict__ b_hh,
                                 float* __restrict__ wd2, float* __restrict__ bA, float* __restrict__ bB) {
  int tid = threadIdx.x;  // 1024 threads, 1 block
  if (tid < HDIM) {
    float d = 0.5f * sigm(b_d[tid]);
    float c = 1.0f;
    for (int i = 0; i < KHIST; ++i) {
      c *= ((float)i - d) / ((float)i + 1.0f);
      wd2[i * HDIM + tid] = c;          // wd2[j-1] = c_j
    }
  }
  for (int n = tid; n < 3 * HDIM; n += 1024) bA[n] = b_mih[n] + b_mhh[n];
  for (int n = tid; n < 4 * HDIM; n += 1024) bB[n] = b_ih[n] + b_hh[n];
}

// ---------------- big input-projection GEMM (fp32 out) ----------------
__global__ __launch_bounds__(256) void gx_gemm_kernel(const unsigned short* __restrict__ Xb,
                                                      const unsigned short* __restrict__ Wb,
                                                      const float* __restrict__ bA,
                                                      float* __restrict__ GX) {
  const int lane = threadIdx.x & 63;
  const int wave = threadIdx.x >> 6;
  const int q = lane >> 4, r16 = lane & 15;
  const int m0 = blockIdx.y * 64 + wave * 16;
  const int n0 = blockIdx.x * 64;
  floatx4 acc[4];
  #pragma unroll
  for (int i = 0; i < 4; ++i) acc[i] = (floatx4){0.f, 0.f, 0.f, 0.f};
  const unsigned short* arow = Xb + (size_t)(m0 + r16) * IDIM;
  #pragma unroll 4
  for (int k0 = 0; k0 < IDIM; k0 += 32) {
    short8 a = *(const short8*)(arow + k0 + q * 8);
    #pragma unroll
    for (int nt = 0; nt < 4; ++nt) {
      short8 b = *(const short8*)(Wb + (size_t)(n0 + nt * 16 + r16) * IDIM + k0 + q * 8);
      acc[nt] = __builtin_amdgcn_mfma_f32_16x16x32_bf16(a, b, acc[nt], 0, 0, 0);
    }
  }
  #pragma unroll
  for (int nt = 0; nt < 4; ++nt) {
    int col = n0 + nt * 16 + r16;
    float bias = bA[col];
    #pragma unroll
    for (int j = 0; j < 4; ++j) {
      int row = m0 + q * 4 + j;
      GX[(size_t)row * 1536 + col] = acc[nt][j] + bias;
    }
  }
}

// ---------------- async persistent recurrent kernel ----------------
// Blocks 0..127: A-blocks (mLSTM cell) = 32 hs x 4 bs (64 rows each)
// Blocks 128..255: B-blocks (LSTMCell) = 32 hs x 4 bs
// Sync: monotone epoch counters aArr[4], bArr[4] (device-scope atomics).
__global__ __launch_bounds__(512, 1) void recurrent2(
    const float* __restrict__ GX,              // (T*256 x 1536) fp32
    const unsigned short* __restrict__ Wmhh,   // (1536 x 512) bf16 N-major
    const unsigned short* __restrict__ W2,     // (2048 x 1024) bf16 N-major
    const float* __restrict__ bB,              // (2048)
    const float* __restrict__ wd2,             // (32 x 512)
    unsigned short* __restrict__ ring,         // (4 x 256 x 512) bf16 h1n ring
    unsigned short* __restrict__ h2buf,        // (2 x 256 x 512) bf16
    float* __restrict__ sel,                   // (256 x 512) fp32
    const int* __restrict__ length,
    int* __restrict__ aArr, int* __restrict__ bArr) {
  extern __shared__ char lds[];
  const int tid = threadIdx.x;
  const int lane = tid & 63;
  const int wv = tid >> 6;                 // 0..7
  const int q = lane >> 4, r16 = lane & 15;
  const bool isA = (int)blockIdx.x < 128;
  const int id = isA ? (int)blockIdx.x : (int)blockIdx.x - 128;
  const int hs = id & 31, bs = id >> 5;
  const int hcol = hs * 16 + r16;

  if (isA) {
    unsigned short* WA = (unsigned short*)lds;                     // [48][520]
    unsigned short* HI = (unsigned short*)(lds + 48 * WA_STRIDE * 2); // hist [32][16 rg][16 c][4 j] bf16
    // stage Wmhh slice (3 gates x 16 cols x 512 K)
    for (int idx = tid; idx < 48 * 64; idx += 512) {
      int rowi = idx >> 6, kc = idx & 63;
      int g = rowi >> 4, c = rowi & 15;
      const unsigned short* src = Wmhh + ((size_t)(g * 512 + hs * 16 + c)) * 512 + kc * 8;
      *(short8*)(WA + rowi * WA_STRIDE + kc * 8) = *(const short8*)src;
    }
    for (int idx = tid; idx < 4096; idx += 512)        // zero hist (64KB)
      ((uint4*)HI)[idx] = (uint4){0, 0, 0, 0};
    float wdr[KHIST];
    #pragma unroll
    for (int l = 0; l < KHIST; ++l) wdr[l] = wd2[l * HDIM + hcol];
    __syncthreads();

    const int mi = wv & 3;
    const int m0 = bs * 64 + mi * 16;
    const int rg = mi * 4 + q;            // row-group within block (rows rg*4+j)

    for (int s = 0; s < T_STEPS; ++s) {
      if (tid == 0) {
        while (__hip_atomic_load(aArr + bs, __ATOMIC_ACQUIRE, __HIP_MEMORY_SCOPE_AGENT) < 32 * s)
          __builtin_amdgcn_s_sleep(2);
        int bt = 32 * (s - (D_RING - 1));
        if (bt > 0)
          while (__hip_atomic_load(bArr + bs, __ATOMIC_ACQUIRE, __HIP_MEMORY_SCOPE_AGENT) < bt)
            __builtin_amdgcn_s_sleep(2);
      }
      __syncthreads();
      if (wv < 4) {
        floatx4 acc[3];
        #pragma unroll
        for (int g = 0; g < 3; ++g) acc[g] = (floatx4){0.f, 0.f, 0.f, 0.f};
        if (s > 0) {
          const unsigned short* arow = ring + ((size_t)((s - 1) & 3) * BATCH + m0 + r16) * 512;
          #pragma unroll 4
          for (int k0 = 0; k0 < 512; k0 += 32) {
            short8 a = *(const short8*)(arow + k0 + q * 8);
            #pragma unroll
            for (int g = 0; g < 3; ++g) {
              short8 b = *(const short8*)(WA + (size_t)(g * 16 + r16) * WA_STRIDE + k0 + q * 8);
              acc[g] = __builtin_amdgcn_mfma_f32_16x16x32_bf16(a, b, acc[g], 0, 0, 0);
            }
          }
        }
        // frac-diff filter from LDS hist
        float f0 = 0.f, f1 = 0.f, f2 = 0.f, f3 = 0.f;
        #pragma unroll
        for (int jj = 1; jj <= KHIST; ++jj) {
          int slot = (s - jj) & (KHIST - 1);
          ushort4 hv = *(const ushort4*)(HI + ((size_t)(slot * 16 + rg) * 16 + r16) * 4);
          float wc = wdr[jj - 1];
          f0 += wc * bf2f(hv.x); f1 += wc * bf2f(hv.y);
          f2 += wc * bf2f(hv.z); f3 += wc * bf2f(hv.w);
        }
        float fj[4] = {f0, f1, f2, f3};
        float c1[4];
        #pragma unroll
        for (int j = 0; j < 4; ++j) {
          int row = m0 + q * 4 + j;
          size_t gidx = ((size_t)s * BATCH + row) * 1536 + hcol;
          float gI = GX[gidx]        + acc[0][j];
          float gO = GX[gidx + 512]  + acc[1][j];
          float gG = GX[gidx + 1024] + acc[2][j];
          float ig = sigm(gI), og = sigm(gO), cd = tanh_f(gG);
          float c1v = ig * cd - fj[j];
          c1[j] = c1v;
          ring[((size_t)(s & 3) * BATCH + row) * 512 + hcol] = f2bf(og * tanh_f(c1v));
        }
        ushort4 hw;
        hw.x = f2bf(c1[0]); hw.y = f2bf(c1[1]); hw.z = f2bf(c1[2]); hw.w = f2bf(c1[3]);
        *(ushort4*)(HI + ((size_t)((s & (KHIST - 1)) * 16 + rg) * 16 + r16) * 4) = hw;
      }
      __threadfence();
      __syncthreads();
      if (tid == 0)
        __hip_atomic_fetch_add(aArr + bs, 1, __ATOMIC_RELEASE, __HIP_MEMORY_SCOPE_AGENT);
    }
  } else {
    // ---- B block ----
    unsigned short* WB = (unsigned short*)lds;                 // [64][1032]
    float* EX = (float*)(lds + 64 * WB_STRIDE * 2);            // exch [4 mi][4 g][64 lane][4]
    for (int idx = tid; idx < 64 * 128; idx += 512) {
      int rowi = idx >> 7, kc = idx & 127;
      int g = rowi >> 4, c = rowi & 15;
      const unsigned short* src = W2 + ((size_t)(g * 512 + hs * 16 + c)) * 1024 + kc * 8;
      *(short8*)(WB + rowi * WB_STRIDE + kc * 8) = *(const short8*)src;
    }
    const int mi = wv >> 1, kh = wv & 1;
    const int m0 = bs * 64 + mi * 16;
    float c2r[4] = {0.f, 0.f, 0.f, 0.f};
    int lenr[4];
    float bBr[4];
    #pragma unroll
    for (int j = 0; j < 4; ++j) lenr[j] = length[m0 + q * 4 + j];
    #pragma unroll
    for (int g = 0; g < 4; ++g) bBr[g] = bB[g * 512 + hcol];
    __syncthreads();

    for (int t = 0; t < T_STEPS; ++t) {
      if (tid == 0) {
        while (__hip_atomic_load(aArr + bs, __ATOMIC_ACQUIRE, __HIP_MEMORY_SCOPE_AGENT) < 32 * (t + 1))
          __builtin_amdgcn_s_sleep(2);
        if (t > 0)
          while (__hip_atomic_load(bArr + bs, __ATOMIC_ACQUIRE, __HIP_MEMORY_SCOPE_AGENT) < 32 * t)
            __builtin_amdgcn_s_sleep(2);
      }
      __syncthreads();
      floatx4 acc[4];
      #pragma unroll
      for (int g = 0; g < 4; ++g) acc[g] = (floatx4){0.f, 0.f, 0.f, 0.f};
      bool doit = true;
      const unsigned short* arow;
      if (kh == 0) {
        arow = ring + ((size_t)(t & 3) * BATCH + m0 + r16) * 512;
      } else {
        if (t == 0) doit = false;
        arow = h2buf + ((size_t)((t - 1) & 1) * BATCH + m0 + r16) * 512;
      }
      if (doit) {
        #pragma unroll 4
        for (int k0 = 0; k0 < 512; k0 += 32) {
          short8 a = *(const short8*)(arow + k0 + q * 8);
          #pragma unroll
          for (int g = 0; g < 4; ++g) {
            short8 b = *(const short8*)(WB + (size_t)(g * 16 + r16) * WB_STRIDE + kh * 512 + k0 + q * 8);
            acc[g] = __builtin_amdgcn_mfma_f32_16x16x32_bf16(a, b, acc[g], 0, 0, 0);
          }
        }
      }
      if (kh == 1) {
        #pragma unroll
        for (int g = 0; g < 4; ++g)
          *(floatx4*)(EX + ((size_t)(mi * 4 + g) * 64 + lane) * 4) = acc[g];
      }
      __syncthreads();
      if (kh == 0) {
        #pragma unroll
        for (int g = 0; g < 4; ++g)
          acc[g] += *(const floatx4*)(EX + ((size_t)(mi * 4 + g) * 64 + lane) * 4);
        #pragma unroll
        for (int j = 0; j < 4; ++j) {
          int row = m0 + q * 4 + j;
          float gi = acc[0][j] + bBr[0];
          float gf = acc[1][j] + bBr[1];
          float gg = acc[2][j] + bBr[2];
          float go = acc[3][j] + bBr[3];
          float c2n = sigm(gf) * c2r[j] + sigm(gi) * tanh_f(gg);
          c2r[j] = c2n;
          float h2n = tanh_f(sigm(go) * tanh_f(c2n));
          h2buf[((size_t)(t & 1) * BATCH + row) * 512 + hcol] = f2bf(h2n);
          if (lenr[j] == t) sel[(size_t)row * 512 + hcol] = h2n;
        }
      }
      __threadfence();
      __syncthreads();
      if (tid == 0)
        __hip_atomic_fetch_add(bArr + bs, 1, __ATOMIC_RELEASE, __HIP_MEMORY_SCOPE_AGENT);
    }
  }
}

// ---------------- output head ----------------
__global__ void out_head_kernel(const float* __restrict__ sel, const float* __restrict__ Wout,
                                const float* __restrict__ bout, float* __restrict__ out) {
  int b = blockIdx.x, lane = threadIdx.x;   // 256 blocks x 64 threads
  float acc[5] = {0.f, 0.f, 0.f, 0.f, 0.f};
  for (int j = lane; j < HDIM; j += 64) {
    float x = sel[(size_t)b * HDIM + j];
    #pragma unroll
    for (int o = 0; o < 5; ++o) acc[o] += x * Wout[o * HDIM + j];
  }
  #pragma unroll
  for (int o = 0; o < 5; ++o)
    for (int off = 32; off > 0; off >>= 1) acc[o] += __shfl_down(acc[o], off);
  if (lane == 0) {
    float v[5]; float m = -1e30f;
    #pragma unroll
    for (int o = 0; o < 5; ++o) { v[o] = acc[o] + bout[o]; m = fmaxf(m, v[o]); }
    float s = 0.f;
    #pragma unroll
    for (int o = 0; o < 5; ++o) s += __expf(v[o] - m);
    float l = logf(s) + m;
    #pragma unroll
    for (int o = 0; o < 5; ++o) out[b * 5 + o] = v[o] - l;
  }
}

// ---------------- launch ----------------
extern "C" void kernel_launch(void* const* d_in, const int* in_sizes, int n_in,
                              void* d_out, int out_size, void* d_ws, size_t ws_size,
                              hipStream_t stream) {
  const float* x      = (const float*)d_in[0];
  const int*   length = (const int*)d_in[1];
  const float* b_d    = (const float*)d_in[2];
  const float* W_mih  = (const float*)d_in[3];
  const float* W_mhh  = (const float*)d_in[4];
  const float* b_mih  = (const float*)d_in[5];
  const float* b_mhh  = (const float*)d_in[6];
  const float* W_ih   = (const float*)d_in[7];
  const float* W_hh   = (const float*)d_in[8];
  const float* b_ih   = (const float*)d_in[9];
  const float* b_hh   = (const float*)d_in[10];
  const float* W_out  = (const float*)d_in[11];
  const float* b_out  = (const float*)d_in[12];
  float* out = (float*)d_out;

  char* ws = (char*)d_ws;
  size_t off = 0;
  auto take = [&](size_t bytes) -> char* {
    char* p = ws + off;
    off += (bytes + 255) & ~(size_t)255;
    return p;
  };

  unsigned short* Xb     = (unsigned short*)take((size_t)T_STEPS * BATCH * IDIM * 2);
  unsigned short* Wmih_b = (unsigned short*)take(1536 * 512 * 2);
  unsigned short* Wmhh_b = (unsigned short*)take(1536 * 512 * 2);
  unsigned short* W2_b   = (unsigned short*)take(2048 * 1024 * 2);
  float* bA  = (float*)take(1536 * 4);
  float* bB  = (float*)take(2048 * 4);
  float* wd2 = (float*)take(KHIST * HDIM * 4);
  unsigned short* ring  = (unsigned short*)take((size_t)D_RING * BATCH * 512 * 2);
  unsigned short* h2buf = (unsigned short*)take((size_t)2 * BATCH * 512 * 2);
  float* sel = (float*)take((size_t)BATCH * HDIM * 4);
  int* counters = (int*)take(256);            // aArr[4], bArr[4]
  int* aArr = counters;
  int* bArr = counters + 4;
  float* GX = (float*)take((size_t)T_STEPS * BATCH * 1536 * 4);
  if (off > ws_size) return;  // workspace too small -> loud validation failure

  hipMemsetAsync(counters, 0, 256, stream);
  prep_misc_kernel<<<1, 1024, 0, stream>>>(b_d, b_mih, b_mhh, b_ih, b_hh, wd2, bA, bB);
  cast4_kernel<<<(T_STEPS * BATCH * IDIM / 4 + 255) / 256, 256, 0, stream>>>(x, Xb, T_STEPS * BATCH * IDIM / 4);
  cast4_kernel<<<(1536 * 512 / 4 + 255) / 256, 256, 0, stream>>>(W_mih, Wmih_b, 1536 * 512 / 4);
  cast4_kernel<<<(1536 * 512 / 4 + 255) / 256, 256, 0, stream>>>(W_mhh, Wmhh_b, 1536 * 512 / 4);
  pack_w2_kernel<<<(2048 * 1024 / 4 + 255) / 256, 256, 0, stream>>>(W_ih, W_hh, W2_b);
  gx_gemm_kernel<<<dim3(1536 / 64, T_STEPS * BATCH / 64), 256, 0, stream>>>(Xb, Wmih_b, bA, GX);

  static bool attr_set = false;
  if (!attr_set) {
    hipFuncSetAttribute((const void*)recurrent2, hipFuncAttributeMaxDynamicSharedMemorySize, LDS_BYTES);
    attr_set = true;
  }
  void* kargs[] = { (void*)&GX, (void*)&Wmhh_b, (void*)&W2_b, (void*)&bB, (void*)&wd2,
                    (void*)&ring, (void*)&h2buf, (void*)&sel, (void*)&length,
                    (void*)&aArr, (void*)&bArr };
  hipLaunchCooperativeKernel((void*)recurrent2, dim3(256), dim3(512), kargs, LDS_BYTES, stream);

  out_head_kernel<<<BATCH, 64, 0, stream>>>(sel, W_out, b_out, out);
}

// Round 3
// 2828.155 us; speedup vs baseline: 3.8114x; 3.6515x over previous
//
#include <hip/hip_runtime.h>
#include <hip/hip_cooperative_groups.h>
#include <cstdint>
#include <cstddef>

typedef __attribute__((ext_vector_type(8))) short short8;   // 8 bf16 (4 VGPRs) MFMA frag
typedef __attribute__((ext_vector_type(4))) float floatx4;  // MFMA accumulator

#define T_STEPS 128
#define BATCH   256
#define IDIM    512
#define HDIM    512
#define KHIST   32
#define D_RING  4

// LDS layout sizes
#define WA_STRIDE 520      // 512 + 8 pad (bank spread)
#define WB_STRIDE 1032     // 1024 + 8 pad
#define LDS_BYTES 148480   // max(WB 64*1032*2 + EX 16384, WA 48*520*2 + HIST 65536)

__device__ __forceinline__ unsigned short f2bf(float x) {
  union { float f; unsigned u; } v; v.f = x;
  unsigned r = v.u + 0x7fffu + ((v.u >> 16) & 1u);   // RNE
  return (unsigned short)(r >> 16);
}
__device__ __forceinline__ float bf2f(unsigned short s) {
  union { unsigned u; float f; } v; v.u = ((unsigned)s) << 16; return v.f;
}
__device__ __forceinline__ float sigm(float x) { return 1.0f / (1.0f + __expf(-x)); }
__device__ __forceinline__ float tanh_f(float x) {
  float ax = fabsf(x);
  float e = __expf(-2.0f * ax);
  float t = (1.0f - e) / (1.0f + e);
  return x < 0.0f ? -t : t;
}

// ---------------- prep kernels ----------------

__global__ void cast4_kernel(const float* __restrict__ src, unsigned short* __restrict__ dst, int n4) {
  int i = blockIdx.x * blockDim.x + threadIdx.x;
  if (i >= n4) return;
  float4 v = reinterpret_cast<const float4*>(src)[i];
  ushort4 o;
  o.x = f2bf(v.x); o.y = f2bf(v.y); o.z = f2bf(v.z); o.w = f2bf(v.w);
  reinterpret_cast<ushort4*>(dst)[i] = o;
}

__global__ void pack_w2_kernel(const float* __restrict__ Wih, const float* __restrict__ Whh,
                               unsigned short* __restrict__ W2) {
  int i4 = blockIdx.x * blockDim.x + threadIdx.x;   // over 2048*1024/4
  if (i4 >= (2048 * 1024 / 4)) return;
  int i = i4 * 4; int n = i >> 10; int k = i & 1023;
  float4 v = (k < 512) ? reinterpret_cast<const float4*>(Wih + n * 512 + k)[0]
                       : reinterpret_cast<const float4*>(Whh + n * 512 + (k - 512))[0];
  ushort4 o;
  o.x = f2bf(v.x); o.y = f2bf(v.y); o.z = f2bf(v.z); o.w = f2bf(v.w);
  reinterpret_cast<ushort4*>(W2 + i)[0] = o;
}

__global__ void prep_misc_kernel(const float* __restrict__ b_d,
                                 const float* __restrict__ b_mih, const float* __restrict__ b_mhh,
                                 const float* __restrict__ b_ih,  const float* __restrict__ b_hh,
                                 float* __restrict__ wd2, float* __restrict__ bA, float* __restrict__ bB) {
  int tid = threadIdx.x;  // 1024 threads, 1 block
  if (tid < HDIM) {
    float d = 0.5f * sigm(b_d[tid]);
    float c = 1.0f;
    for (int i = 0; i < KHIST; ++i) {
      c *= ((float)i - d) / ((float)i + 1.0f);
      wd2[i * HDIM + tid] = c;          // wd2[j-1] = c_j
    }
  }
  for (int n = tid; n < 3 * HDIM; n += 1024) bA[n] = b_mih[n] + b_mhh[n];
  for (int n = tid; n < 4 * HDIM; n += 1024) bB[n] = b_ih[n] + b_hh[n];
}

// ---------------- big input-projection GEMM (fp32 out) ----------------
__global__ __launch_bounds__(256) void gx_gemm_kernel(const unsigned short* __restrict__ Xb,
                                                      const unsigned short* __restrict__ Wb,
                                                      const float* __restrict__ bA,
                                                      float* __restrict__ GX) {
  const int lane = threadIdx.x & 63;
  const int wave = threadIdx.x >> 6;
  const int q = lane >> 4, r16 = lane & 15;
  const int m0 = blockIdx.y * 64 + wave * 16;
  const int n0 = blockIdx.x * 64;
  floatx4 acc[4];
  #pragma unroll
  for (int i = 0; i < 4; ++i) acc[i] = (floatx4){0.f, 0.f, 0.f, 0.f};
  const unsigned short* arow = Xb + (size_t)(m0 + r16) * IDIM;
  #pragma unroll 4
  for (int k0 = 0; k0 < IDIM; k0 += 32) {
    short8 a = *(const short8*)(arow + k0 + q * 8);
    #pragma unroll
    for (int nt = 0; nt < 4; ++nt) {
      short8 b = *(const short8*)(Wb + (size_t)(n0 + nt * 16 + r16) * IDIM + k0 + q * 8);
      acc[nt] = __builtin_amdgcn_mfma_f32_16x16x32_bf16(a, b, acc[nt], 0, 0, 0);
    }
  }
  #pragma unroll
  for (int nt = 0; nt < 4; ++nt) {
    int col = n0 + nt * 16 + r16;
    float bias = bA[col];
    #pragma unroll
    for (int j = 0; j < 4; ++j) {
      int row = m0 + q * 4 + j;
      GX[(size_t)row * 1536 + col] = acc[nt][j] + bias;
    }
  }
}

// ---------------- async persistent recurrent kernel ----------------
// 256 blocks, XCD-swizzled: xcd = blk&7, slot = blk>>3.
//   group bs = xcd>>1 (4 batch groups of 64 rows)
//   role: A (mLSTM) if xcd even, B (LSTMCell) if odd; hs = slot (32 h-slices)
// Sync: per-group monotone epoch counters, 256B apart. Protocol per step:
//   tid0 acquire-poll -> __syncthreads -> compute -> __syncthreads -> tid0 release-add.
// (__syncthreads drains each wave's stores to L2; tid0's RELEASE does the agent flush.)
__global__ __launch_bounds__(512, 1) void recurrent2(
    const float* __restrict__ GX,              // (T*256 x 1536) fp32
    const unsigned short* __restrict__ Wmhh,   // (1536 x 512) bf16 N-major
    const unsigned short* __restrict__ W2,     // (2048 x 1024) bf16 N-major
    const float* __restrict__ bB,              // (2048)
    const float* __restrict__ wd2,             // (32 x 512)
    unsigned short* __restrict__ ring,         // (4 x 256 x 512) bf16 h1n ring
    unsigned short* __restrict__ h2buf,        // (2 x 256 x 512) bf16
    float* __restrict__ sel,                   // (256 x 512) fp32
    const int* __restrict__ length,
    int* __restrict__ counters) {              // 512 ints: aF at bs*64, bF at 256+bs*64
  extern __shared__ char lds[];
  const int tid = threadIdx.x;
  const int lane = tid & 63;
  const int wv = tid >> 6;                 // 0..7
  const int q = lane >> 4, r16 = lane & 15;
  const int xcd = (int)blockIdx.x & 7;
  const int slot = (int)blockIdx.x >> 3;
  const int bs = xcd >> 1;
  const bool isA = (xcd & 1) == 0;
  const int hs = slot;
  const int hcol = hs * 16 + r16;
  int* aF = counters + bs * 64;            // 256B-separated cachelines
  int* bF = counters + 256 + bs * 64;

  if (isA) {
    unsigned short* WA = (unsigned short*)lds;                        // [48][520]
    unsigned short* HI = (unsigned short*)(lds + 48 * WA_STRIDE * 2); // hist [32][16 rg][16 c][4 j] bf16
    for (int idx = tid; idx < 48 * 64; idx += 512) {
      int rowi = idx >> 6, kc = idx & 63;
      int g = rowi >> 4, c = rowi & 15;
      const unsigned short* src = Wmhh + ((size_t)(g * 512 + hs * 16 + c)) * 512 + kc * 8;
      *(short8*)(WA + rowi * WA_STRIDE + kc * 8) = *(const short8*)src;
    }
    for (int idx = tid; idx < 4096; idx += 512)        // zero hist (64KB)
      ((uint4*)HI)[idx] = (uint4){0, 0, 0, 0};
    float wdr[KHIST];
    #pragma unroll
    for (int l = 0; l < KHIST; ++l) wdr[l] = wd2[l * HDIM + hcol];
    __syncthreads();

    const int mi = wv & 3;
    const int m0 = bs * 64 + mi * 16;
    const int rg = mi * 4 + q;            // row-group within block (rows rg*4+j)

    for (int s = 0; s < T_STEPS; ++s) {
      // prefetch GX for this step into registers BEFORE the wait (constant data,
      // immune to the acquire's L2 invalidate; loads complete during the spin)
      float gx0[4], gx1[4], gx2[4];
      if (wv < 4) {
        #pragma unroll
        for (int j = 0; j < 4; ++j) {
          int row = m0 + q * 4 + j;
          size_t gidx = ((size_t)s * BATCH + row) * 1536 + hcol;
          gx0[j] = GX[gidx];
          gx1[j] = GX[gidx + 512];
          gx2[j] = GX[gidx + 1024];
        }
      }
      if (tid == 0) {
        while (__hip_atomic_load(aF, __ATOMIC_ACQUIRE, __HIP_MEMORY_SCOPE_AGENT) < 32 * s)
          __builtin_amdgcn_s_sleep(1);
        int bt = 32 * (s - (D_RING - 1));
        if (bt > 0)
          while (__hip_atomic_load(bF, __ATOMIC_ACQUIRE, __HIP_MEMORY_SCOPE_AGENT) < bt)
            __builtin_amdgcn_s_sleep(1);
      }
      __syncthreads();
      if (wv < 4) {
        floatx4 acc[3];
        #pragma unroll
        for (int g = 0; g < 3; ++g) acc[g] = (floatx4){0.f, 0.f, 0.f, 0.f};
        if (s > 0) {
          const unsigned short* arow = ring + ((size_t)((s - 1) & 3) * BATCH + m0 + r16) * 512;
          #pragma unroll 4
          for (int k0 = 0; k0 < 512; k0 += 32) {
            short8 a = *(const short8*)(arow + k0 + q * 8);
            #pragma unroll
            for (int g = 0; g < 3; ++g) {
              short8 b = *(const short8*)(WA + (size_t)(g * 16 + r16) * WA_STRIDE + k0 + q * 8);
              acc[g] = __builtin_amdgcn_mfma_f32_16x16x32_bf16(a, b, acc[g], 0, 0, 0);
            }
          }
        }
        // frac-diff filter from LDS hist
        float f0 = 0.f, f1 = 0.f, f2 = 0.f, f3 = 0.f;
        #pragma unroll
        for (int jj = 1; jj <= KHIST; ++jj) {
          int sl = (s - jj) & (KHIST - 1);
          ushort4 hv = *(const ushort4*)(HI + ((size_t)(sl * 16 + rg) * 16 + r16) * 4);
          float wc = wdr[jj - 1];
          f0 += wc * bf2f(hv.x); f1 += wc * bf2f(hv.y);
          f2 += wc * bf2f(hv.z); f3 += wc * bf2f(hv.w);
        }
        float fj[4] = {f0, f1, f2, f3};
        float c1[4];
        #pragma unroll
        for (int j = 0; j < 4; ++j) {
          int row = m0 + q * 4 + j;
          float gI = gx0[j] + acc[0][j];
          float gO = gx1[j] + acc[1][j];
          float gG = gx2[j] + acc[2][j];
          float ig = sigm(gI), og = sigm(gO), cd = tanh_f(gG);
          float c1v = ig * cd - fj[j];
          c1[j] = c1v;
          ring[((size_t)(s & 3) * BATCH + row) * 512 + hcol] = f2bf(og * tanh_f(c1v));
        }
        ushort4 hw;
        hw.x = f2bf(c1[0]); hw.y = f2bf(c1[1]); hw.z = f2bf(c1[2]); hw.w = f2bf(c1[3]);
        *(ushort4*)(HI + ((size_t)((s & (KHIST - 1)) * 16 + rg) * 16 + r16) * 4) = hw;
      }
      __syncthreads();   // drains all waves' ring stores to L2 (vmcnt(0) at barrier)
      if (tid == 0)
        __hip_atomic_fetch_add(aF, 1, __ATOMIC_RELEASE, __HIP_MEMORY_SCOPE_AGENT);
    }
  } else {
    // ---- B block ----
    unsigned short* WB = (unsigned short*)lds;                 // [64][1032]
    float* EX = (float*)(lds + 64 * WB_STRIDE * 2);            // exch [4 mi][4 g][64 lane][4]
    for (int idx = tid; idx < 64 * 128; idx += 512) {
      int rowi = idx >> 7, kc = idx & 127;
      int g = rowi >> 4, c = rowi & 15;
      const unsigned short* src = W2 + ((size_t)(g * 512 + hs * 16 + c)) * 1024 + kc * 8;
      *(short8*)(WB + rowi * WB_STRIDE + kc * 8) = *(const short8*)src;
    }
    const int mi = wv >> 1, kh = wv & 1;
    const int m0 = bs * 64 + mi * 16;
    float c2r[4] = {0.f, 0.f, 0.f, 0.f};
    int lenr[4];
    float bBr[4];
    #pragma unroll
    for (int j = 0; j < 4; ++j) lenr[j] = length[m0 + q * 4 + j];
    #pragma unroll
    for (int g = 0; g < 4; ++g) bBr[g] = bB[g * 512 + hcol];
    __syncthreads();

    for (int t = 0; t < T_STEPS; ++t) {
      if (tid == 0) {
        while (__hip_atomic_load(aF, __ATOMIC_ACQUIRE, __HIP_MEMORY_SCOPE_AGENT) < 32 * (t + 1))
          __builtin_amdgcn_s_sleep(1);
        if (t > 0)
          while (__hip_atomic_load(bF, __ATOMIC_ACQUIRE, __HIP_MEMORY_SCOPE_AGENT) < 32 * t)
            __builtin_amdgcn_s_sleep(1);
      }
      __syncthreads();
      floatx4 acc[4];
      #pragma unroll
      for (int g = 0; g < 4; ++g) acc[g] = (floatx4){0.f, 0.f, 0.f, 0.f};
      bool doit = true;
      const unsigned short* arow;
      if (kh == 0) {
        arow = ring + ((size_t)(t & 3) * BATCH + m0 + r16) * 512;
      } else {
        if (t == 0) doit = false;
        arow = h2buf + ((size_t)((t - 1) & 1) * BATCH + m0 + r16) * 512;
      }
      if (doit) {
        #pragma unroll 4
        for (int k0 = 0; k0 < 512; k0 += 32) {
          short8 a = *(const short8*)(arow + k0 + q * 8);
          #pragma unroll
          for (int g = 0; g < 4; ++g) {
            short8 b = *(const short8*)(WB + (size_t)(g * 16 + r16) * WB_STRIDE + kh * 512 + k0 + q * 8);
            acc[g] = __builtin_amdgcn_mfma_f32_16x16x32_bf16(a, b, acc[g], 0, 0, 0);
          }
        }
      }
      if (kh == 1) {
        #pragma unroll
        for (int g = 0; g < 4; ++g)
          *(floatx4*)(EX + ((size_t)(mi * 4 + g) * 64 + lane) * 4) = acc[g];
      }
      __syncthreads();
      if (kh == 0) {
        #pragma unroll
        for (int g = 0; g < 4; ++g)
          acc[g] += *(const floatx4*)(EX + ((size_t)(mi * 4 + g) * 64 + lane) * 4);
        #pragma unroll
        for (int j = 0; j < 4; ++j) {
          int row = m0 + q * 4 + j;
          float gi = acc[0][j] + bBr[0];
          float gf = acc[1][j] + bBr[1];
          float gg = acc[2][j] + bBr[2];
          float go = acc[3][j] + bBr[3];
          float c2n = sigm(gf) * c2r[j] + sigm(gi) * tanh_f(gg);
          c2r[j] = c2n;
          float h2n = tanh_f(sigm(go) * tanh_f(c2n));
          h2buf[((size_t)(t & 1) * BATCH + row) * 512 + hcol] = f2bf(h2n);
          if (lenr[j] == t) sel[(size_t)row * 512 + hcol] = h2n;
        }
      }
      __syncthreads();   // drains h2buf/sel stores of all waves
      if (tid == 0)
        __hip_atomic_fetch_add(bF, 1, __ATOMIC_RELEASE, __HIP_MEMORY_SCOPE_AGENT);
    }
  }
}

// ---------------- output head ----------------
__global__ void out_head_kernel(const float* __restrict__ sel, const float* __restrict__ Wout,
                                const float* __restrict__ bout, float* __restrict__ out) {
  int b = blockIdx.x, lane = threadIdx.x;   // 256 blocks x 64 threads
  float acc[5] = {0.f, 0.f, 0.f, 0.f, 0.f};
  for (int j = lane; j < HDIM; j += 64) {
    float x = sel[(size_t)b * HDIM + j];
    #pragma unroll
    for (int o = 0; o < 5; ++o) acc[o] += x * Wout[o * HDIM + j];
  }
  #pragma unroll
  for (int o = 0; o < 5; ++o)
    for (int off = 32; off > 0; off >>= 1) acc[o] += __shfl_down(acc[o], off);
  if (lane == 0) {
    float v[5]; float m = -1e30f;
    #pragma unroll
    for (int o = 0; o < 5; ++o) { v[o] = acc[o] + bout[o]; m = fmaxf(m, v[o]); }
    float s = 0.f;
    #pragma unroll
    for (int o = 0; o < 5; ++o) s += __expf(v[o] - m);
    float l = logf(s) + m;
    #pragma unroll
    for (int o = 0; o < 5; ++o) out[b * 5 + o] = v[o] - l;
  }
}

// ---------------- launch ----------------
extern "C" void kernel_launch(void* const* d_in, const int* in_sizes, int n_in,
                              void* d_out, int out_size, void* d_ws, size_t ws_size,
                              hipStream_t stream) {
  const float* x      = (const float*)d_in[0];
  const int*   length = (const int*)d_in[1];
  const float* b_d    = (const float*)d_in[2];
  const float* W_mih  = (const float*)d_in[3];
  const float* W_mhh  = (const float*)d_in[4];
  const float* b_mih  = (const float*)d_in[5];
  const float* b_mhh  = (const float*)d_in[6];
  const float* W_ih   = (const float*)d_in[7];
  const float* W_hh   = (const float*)d_in[8];
  const float* b_ih   = (const float*)d_in[9];
  const float* b_hh   = (const float*)d_in[10];
  const float* W_out  = (const float*)d_in[11];
  const float* b_out  = (const float*)d_in[12];
  float* out = (float*)d_out;

  char* ws = (char*)d_ws;
  size_t off = 0;
  auto take = [&](size_t bytes) -> char* {
    char* p = ws + off;
    off += (bytes + 255) & ~(size_t)255;
    return p;
  };

  unsigned short* Xb     = (unsigned short*)take((size_t)T_STEPS * BATCH * IDIM * 2);
  unsigned short* Wmih_b = (unsigned short*)take(1536 * 512 * 2);
  unsigned short* Wmhh_b = (unsigned short*)take(1536 * 512 * 2);
  unsigned short* W2_b   = (unsigned short*)take(2048 * 1024 * 2);
  float* bA  = (float*)take(1536 * 4);
  float* bB  = (float*)take(2048 * 4);
  float* wd2 = (float*)take(KHIST * HDIM * 4);
  unsigned short* ring  = (unsigned short*)take((size_t)D_RING * BATCH * 512 * 2);
  unsigned short* h2buf = (unsigned short*)take((size_t)2 * BATCH * 512 * 2);
  float* sel = (float*)take((size_t)BATCH * HDIM * 4);
  int* counters = (int*)take(2048);           // aF at bs*64 ints, bF at 256+bs*64 ints
  float* GX = (float*)take((size_t)T_STEPS * BATCH * 1536 * 4);
  if (off > ws_size) return;  // workspace too small -> loud validation failure

  hipMemsetAsync(counters, 0, 2048, stream);
  prep_misc_kernel<<<1, 1024, 0, stream>>>(b_d, b_mih, b_mhh, b_ih, b_hh, wd2, bA, bB);
  cast4_kernel<<<(T_STEPS * BATCH * IDIM / 4 + 255) / 256, 256, 0, stream>>>(x, Xb, T_STEPS * BATCH * IDIM / 4);
  cast4_kernel<<<(1536 * 512 / 4 + 255) / 256, 256, 0, stream>>>(W_mih, Wmih_b, 1536 * 512 / 4);
  cast4_kernel<<<(1536 * 512 / 4 + 255) / 256, 256, 0, stream>>>(W_mhh, Wmhh_b, 1536 * 512 / 4);
  pack_w2_kernel<<<(2048 * 1024 / 4 + 255) / 256, 256, 0, stream>>>(W_ih, W_hh, W2_b);
  gx_gemm_kernel<<<dim3(1536 / 64, T_STEPS * BATCH / 64), 256, 0, stream>>>(Xb, Wmih_b, bA, GX);

  hipFuncSetAttribute((const void*)recurrent2, hipFuncAttributeMaxDynamicSharedMemorySize, LDS_BYTES);
  void* kargs[] = { (void*)&GX, (void*)&Wmhh_b, (void*)&W2_b, (void*)&bB, (void*)&wd2,
                    (void*)&ring, (void*)&h2buf, (void*)&sel, (void*)&length,
                    (void*)&counters };
  hipLaunchCooperativeKernel((void*)recurrent2, dim3(256), dim3(512), kargs, LDS_BYTES, stream);

  out_head_kernel<<<BATCH, 64, 0, stream>>>(sel, W_out, b_out, out);
}

// Round 4
// 2305.396 us; speedup vs baseline: 4.6757x; 1.2268x over previous
//
#include <hip/hip_runtime.h>
#include <hip/hip_cooperative_groups.h>
#include <cstdint>
#include <cstddef>

typedef __attribute__((ext_vector_type(8))) short short8;   // 8 bf16 (4 VGPRs) MFMA frag
typedef __attribute__((ext_vector_type(4))) float floatx4;  // MFMA accumulator

#define T_STEPS 128
#define BATCH   256
#define IDIM    512
#define HDIM    512
#define KHIST   32
#define D_RING  4

// LDS layout sizes
#define WA_STRIDE 520      // 512 + 8 pad (bank spread)
#define WB_STRIDE 1032     // 1024 + 8 pad
#define LDS_BYTES 148480   // max(WB 64*1032*2 + EX 16384, WA 48*520*2 + HIST 65536)

__device__ __forceinline__ unsigned short f2bf(float x) {
  union { float f; unsigned u; } v; v.f = x;
  unsigned r = v.u + 0x7fffu + ((v.u >> 16) & 1u);   // RNE
  return (unsigned short)(r >> 16);
}
__device__ __forceinline__ float bf2f(unsigned short s) {
  union { unsigned u; float f; } v; v.u = ((unsigned)s) << 16; return v.f;
}
__device__ __forceinline__ float sigm(float x) { return 1.0f / (1.0f + __expf(-x)); }
__device__ __forceinline__ float tanh_f(float x) {
  float ax = fabsf(x);
  float e = __expf(-2.0f * ax);
  float t = (1.0f - e) / (1.0f + e);
  return x < 0.0f ? -t : t;
}

// ---------------- prep kernels ----------------

__global__ void cast4_kernel(const float* __restrict__ src, unsigned short* __restrict__ dst, int n4) {
  int i = blockIdx.x * blockDim.x + threadIdx.x;
  if (i >= n4) return;
  float4 v = reinterpret_cast<const float4*>(src)[i];
  ushort4 o;
  o.x = f2bf(v.x); o.y = f2bf(v.y); o.z = f2bf(v.z); o.w = f2bf(v.w);
  reinterpret_cast<ushort4*>(dst)[i] = o;
}

__global__ void pack_w2_kernel(const float* __restrict__ Wih, const float* __restrict__ Whh,
                               unsigned short* __restrict__ W2) {
  int i4 = blockIdx.x * blockDim.x + threadIdx.x;   // over 2048*1024/4
  if (i4 >= (2048 * 1024 / 4)) return;
  int i = i4 * 4; int n = i >> 10; int k = i & 1023;
  float4 v = (k < 512) ? reinterpret_cast<const float4*>(Wih + n * 512 + k)[0]
                       : reinterpret_cast<const float4*>(Whh + n * 512 + (k - 512))[0];
  ushort4 o;
  o.x = f2bf(v.x); o.y = f2bf(v.y); o.z = f2bf(v.z); o.w = f2bf(v.w);
  reinterpret_cast<ushort4*>(W2 + i)[0] = o;
}

__global__ void prep_misc_kernel(const float* __restrict__ b_d,
                                 const float* __restrict__ b_mih, const float* __restrict__ b_mhh,
                                 const float* __restrict__ b_ih,  const float* __restrict__ b_hh,
                                 float* __restrict__ wd2, float* __restrict__ bA, float* __restrict__ bB) {
  int tid = threadIdx.x;  // 1024 threads, 1 block
  if (tid < HDIM) {
    float d = 0.5f * sigm(b_d[tid]);
    float c = 1.0f;
    for (int i = 0; i < KHIST; ++i) {
      c *= ((float)i - d) / ((float)i + 1.0f);
      wd2[i * HDIM + tid] = c;          // wd2[j-1] = c_j
    }
  }
  for (int n = tid; n < 3 * HDIM; n += 1024) bA[n] = b_mih[n] + b_mhh[n];
  for (int n = tid; n < 4 * HDIM; n += 1024) bB[n] = b_ih[n] + b_hh[n];
}

// ---------------- big input-projection GEMM (fp32 out) ----------------
__global__ __launch_bounds__(256) void gx_gemm_kernel(const unsigned short* __restrict__ Xb,
                                                      const unsigned short* __restrict__ Wb,
                                                      const float* __restrict__ bA,
                                                      float* __restrict__ GX) {
  const int lane = threadIdx.x & 63;
  const int wave = threadIdx.x >> 6;
  const int q = lane >> 4, r16 = lane & 15;
  const int m0 = blockIdx.y * 64 + wave * 16;
  const int n0 = blockIdx.x * 64;
  floatx4 acc[4];
  #pragma unroll
  for (int i = 0; i < 4; ++i) acc[i] = (floatx4){0.f, 0.f, 0.f, 0.f};
  const unsigned short* arow = Xb + (size_t)(m0 + r16) * IDIM;
  #pragma unroll 4
  for (int k0 = 0; k0 < IDIM; k0 += 32) {
    short8 a = *(const short8*)(arow + k0 + q * 8);
    #pragma unroll
    for (int nt = 0; nt < 4; ++nt) {
      short8 b = *(const short8*)(Wb + (size_t)(n0 + nt * 16 + r16) * IDIM + k0 + q * 8);
      acc[nt] = __builtin_amdgcn_mfma_f32_16x16x32_bf16(a, b, acc[nt], 0, 0, 0);
    }
  }
  #pragma unroll
  for (int nt = 0; nt < 4; ++nt) {
    int col = n0 + nt * 16 + r16;
    float bias = bA[col];
    #pragma unroll
    for (int j = 0; j < 4; ++j) {
      int row = m0 + q * 4 + j;
      GX[(size_t)row * 1536 + col] = acc[nt][j] + bias;
    }
  }
}

// ---------------- async persistent recurrent kernel ----------------
// 256 blocks, XCD-swizzled: xcd = blk&7, slot = blk>>3.
//   group bs = xcd>>1 (4 batch groups of 64 rows)
//   role: A (mLSTM) if xcd even, B (LSTMCell) if odd; hs = slot (32 h-slices)
// Sync: per-BLOCK flag slots (release STORE, no RMW convoy). Consumers poll all
// 32 producer flags with one lane each (lanes 0..31 = A-flags, 32..63 = B-flags),
// relaxed loads + one agent acquire fence once satisfied.
__global__ __launch_bounds__(512, 1) void recurrent2(
    const float* __restrict__ GX,              // (T*256 x 1536) fp32
    const unsigned short* __restrict__ Wmhh,   // (1536 x 512) bf16 N-major
    const unsigned short* __restrict__ W2,     // (2048 x 1024) bf16 N-major
    const float* __restrict__ bB,              // (2048)
    const float* __restrict__ wd2,             // (32 x 512)
    unsigned short* __restrict__ ring,         // (4 x 256 x 512) bf16 h1n ring
    unsigned short* __restrict__ h2buf,        // (2 x 256 x 512) bf16
    float* __restrict__ sel,                   // (256 x 512) fp32
    const int* __restrict__ length,
    int* __restrict__ counters) {              // 2048 ints; aFlags at bs*64, bFlags at 1024+bs*64
  extern __shared__ char lds[];
  const int tid = threadIdx.x;
  const int lane = tid & 63;
  const int wv = tid >> 6;                 // 0..7
  const int q = lane >> 4, r16 = lane & 15;
  const int xcd = (int)blockIdx.x & 7;
  const int slot = (int)blockIdx.x >> 3;
  const int bs = xcd >> 1;
  const bool isA = (xcd & 1) == 0;
  const int hs = slot;
  const int hcol = hs * 16 + r16;
  int* aFlags = counters + bs * 64;            // 32 ints used, 256B spacing per group
  int* bFlags = counters + 1024 + bs * 64;

  if (isA) {
    unsigned short* WA = (unsigned short*)lds;                        // [48][520]
    unsigned short* HI = (unsigned short*)(lds + 48 * WA_STRIDE * 2); // hist [32][16 rg][16 c][4 j] bf16
    for (int idx = tid; idx < 48 * 64; idx += 512) {
      int rowi = idx >> 6, kc = idx & 63;
      int g = rowi >> 4, c = rowi & 15;
      const unsigned short* src = Wmhh + ((size_t)(g * 512 + hs * 16 + c)) * 512 + kc * 8;
      *(short8*)(WA + rowi * WA_STRIDE + kc * 8) = *(const short8*)src;
    }
    for (int idx = tid; idx < 4096; idx += 512)        // zero hist (64KB)
      ((uint4*)HI)[idx] = (uint4){0, 0, 0, 0};
    float wdr[KHIST];
    #pragma unroll
    for (int l = 0; l < KHIST; ++l) wdr[l] = wd2[l * HDIM + hcol];
    __syncthreads();

    const int mi = wv & 3;
    const int m0 = bs * 64 + mi * 16;
    const int rg = mi * 4 + q;            // row-group within block (rows rg*4+j)

    for (int s = 0; s < T_STEPS; ++s) {
      // prefetch GX for this step into registers BEFORE the wait (constant data,
      // loads complete during the spin; immune to the acquire invalidate)
      float gx0[4], gx1[4], gx2[4];
      if (wv < 4) {
        #pragma unroll
        for (int j = 0; j < 4; ++j) {
          int row = m0 + q * 4 + j;
          size_t gidx = ((size_t)s * BATCH + row) * 1536 + hcol;
          gx0[j] = GX[gidx];
          gx1[j] = GX[gidx + 512];
          gx2[j] = GX[gidx + 1024];
        }
      }
      if (wv == 0) {
        const int* f; int tgt;
        if (lane < 32) { f = aFlags + lane; tgt = s; }                 // peers done s-1
        else           { f = bFlags + (lane - 32); tgt = s - (D_RING - 1); }  // ring slot free
        if (tgt > 0)
          while (__hip_atomic_load(f, __ATOMIC_RELAXED, __HIP_MEMORY_SCOPE_AGENT) < tgt)
            __builtin_amdgcn_s_sleep(2);
        __builtin_amdgcn_fence(__ATOMIC_ACQUIRE, "agent");
      }
      __syncthreads();
      if (wv < 4) {
        floatx4 acc[3];
        #pragma unroll
        for (int g = 0; g < 3; ++g) acc[g] = (floatx4){0.f, 0.f, 0.f, 0.f};
        if (s > 0) {
          const unsigned short* arow = ring + ((size_t)((s - 1) & 3) * BATCH + m0 + r16) * 512;
          #pragma unroll 4
          for (int k0 = 0; k0 < 512; k0 += 32) {
            short8 a = *(const short8*)(arow + k0 + q * 8);
            #pragma unroll
            for (int g = 0; g < 3; ++g) {
              short8 b = *(const short8*)(WA + (size_t)(g * 16 + r16) * WA_STRIDE + k0 + q * 8);
              acc[g] = __builtin_amdgcn_mfma_f32_16x16x32_bf16(a, b, acc[g], 0, 0, 0);
            }
          }
        }
        // frac-diff filter from LDS hist
        float f0 = 0.f, f1 = 0.f, f2 = 0.f, f3 = 0.f;
        #pragma unroll
        for (int jj = 1; jj <= KHIST; ++jj) {
          int sl = (s - jj) & (KHIST - 1);
          ushort4 hv = *(const ushort4*)(HI + ((size_t)(sl * 16 + rg) * 16 + r16) * 4);
          float wc = wdr[jj - 1];
          f0 += wc * bf2f(hv.x); f1 += wc * bf2f(hv.y);
          f2 += wc * bf2f(hv.z); f3 += wc * bf2f(hv.w);
        }
        float fj[4] = {f0, f1, f2, f3};
        float c1[4];
        #pragma unroll
        for (int j = 0; j < 4; ++j) {
          int row = m0 + q * 4 + j;
          float gI = gx0[j] + acc[0][j];
          float gO = gx1[j] + acc[1][j];
          float gG = gx2[j] + acc[2][j];
          float ig = sigm(gI), og = sigm(gO), cd = tanh_f(gG);
          float c1v = ig * cd - fj[j];
          c1[j] = c1v;
          ring[((size_t)(s & 3) * BATCH + row) * 512 + hcol] = f2bf(og * tanh_f(c1v));
        }
        ushort4 hw;
        hw.x = f2bf(c1[0]); hw.y = f2bf(c1[1]); hw.z = f2bf(c1[2]); hw.w = f2bf(c1[3]);
        *(ushort4*)(HI + ((size_t)((s & (KHIST - 1)) * 16 + rg) * 16 + r16) * 4) = hw;
      }
      __syncthreads();   // drains all waves' ring stores to L2 (vmcnt(0) at barrier)
      if (tid == 0)
        __hip_atomic_store(aFlags + hs, s + 1, __ATOMIC_RELEASE, __HIP_MEMORY_SCOPE_AGENT);
    }
  } else {
    // ---- B block ----
    unsigned short* WB = (unsigned short*)lds;                 // [64][1032]
    float* EX = (float*)(lds + 64 * WB_STRIDE * 2);            // exch [4 mi][4 g][64 lane][4]
    for (int idx = tid; idx < 64 * 128; idx += 512) {
      int rowi = idx >> 7, kc = idx & 127;
      int g = rowi >> 4, c = rowi & 15;
      const unsigned short* src = W2 + ((size_t)(g * 512 + hs * 16 + c)) * 1024 + kc * 8;
      *(short8*)(WB + rowi * WB_STRIDE + kc * 8) = *(const short8*)src;
    }
    const int mi = wv >> 1, kh = wv & 1;
    const int m0 = bs * 64 + mi * 16;
    float c2r[4] = {0.f, 0.f, 0.f, 0.f};
    int lenr[4];
    float bBr[4];
    #pragma unroll
    for (int j = 0; j < 4; ++j) lenr[j] = length[m0 + q * 4 + j];
    #pragma unroll
    for (int g = 0; g < 4; ++g) bBr[g] = bB[g * 512 + hcol];
    __syncthreads();

    for (int t = 0; t < T_STEPS; ++t) {
      if (wv == 0) {
        const int* f; int tgt;
        if (lane < 32) { f = aFlags + lane; tgt = t + 1; }             // A done t
        else           { f = bFlags + (lane - 32); tgt = t; }          // B peers done t-1
        if (tgt > 0)
          while (__hip_atomic_load(f, __ATOMIC_RELAXED, __HIP_MEMORY_SCOPE_AGENT) < tgt)
            __builtin_amdgcn_s_sleep(2);
        __builtin_amdgcn_fence(__ATOMIC_ACQUIRE, "agent");
      }
      __syncthreads();
      floatx4 acc[4];
      #pragma unroll
      for (int g = 0; g < 4; ++g) acc[g] = (floatx4){0.f, 0.f, 0.f, 0.f};
      bool doit = true;
      const unsigned short* arow;
      if (kh == 0) {
        arow = ring + ((size_t)(t & 3) * BATCH + m0 + r16) * 512;
      } else {
        if (t == 0) doit = false;
        arow = h2buf + ((size_t)((t - 1) & 1) * BATCH + m0 + r16) * 512;
      }
      if (doit) {
        #pragma unroll 4
        for (int k0 = 0; k0 < 512; k0 += 32) {
          short8 a = *(const short8*)(arow + k0 + q * 8);
          #pragma unroll
          for (int g = 0; g < 4; ++g) {
            short8 b = *(const short8*)(WB + (size_t)(g * 16 + r16) * WB_STRIDE + kh * 512 + k0 + q * 8);
            acc[g] = __builtin_amdgcn_mfma_f32_16x16x32_bf16(a, b, acc[g], 0, 0, 0);
          }
        }
      }
      if (kh == 1) {
        #pragma unroll
        for (int g = 0; g < 4; ++g)
          *(floatx4*)(EX + ((size_t)(mi * 4 + g) * 64 + lane) * 4) = acc[g];
      }
      __syncthreads();
      if (kh == 0) {
        #pragma unroll
        for (int g = 0; g < 4; ++g)
          acc[g] += *(const floatx4*)(EX + ((size_t)(mi * 4 + g) * 64 + lane) * 4);
        #pragma unroll
        for (int j = 0; j < 4; ++j) {
          int row = m0 + q * 4 + j;
          float gi = acc[0][j] + bBr[0];
          float gf = acc[1][j] + bBr[1];
          float gg = acc[2][j] + bBr[2];
          float go = acc[3][j] + bBr[3];
          float c2n = sigm(gf) * c2r[j] + sigm(gi) * tanh_f(gg);
          c2r[j] = c2n;
          float h2n = tanh_f(sigm(go) * tanh_f(c2n));
          h2buf[((size_t)(t & 1) * BATCH + row) * 512 + hcol] = f2bf(h2n);
          if (lenr[j] == t) sel[(size_t)row * 512 + hcol] = h2n;
        }
      }
      __syncthreads();   // drains h2buf/sel stores of all waves
      if (tid == 0)
        __hip_atomic_store(bFlags + hs, t + 1, __ATOMIC_RELEASE, __HIP_MEMORY_SCOPE_AGENT);
    }
  }
}

// ---------------- output head ----------------
__global__ void out_head_kernel(const float* __restrict__ sel, const float* __restrict__ Wout,
                                const float* __restrict__ bout, float* __restrict__ out) {
  int b = blockIdx.x, lane = threadIdx.x;   // 256 blocks x 64 threads
  float acc[5] = {0.f, 0.f, 0.f, 0.f, 0.f};
  for (int j = lane; j < HDIM; j += 64) {
    float x = sel[(size_t)b * HDIM + j];
    #pragma unroll
    for (int o = 0; o < 5; ++o) acc[o] += x * Wout[o * HDIM + j];
  }
  #pragma unroll
  for (int o = 0; o < 5; ++o)
    for (int off = 32; off > 0; off >>= 1) acc[o] += __shfl_down(acc[o], off);
  if (lane == 0) {
    float v[5]; float m = -1e30f;
    #pragma unroll
    for (int o = 0; o < 5; ++o) { v[o] = acc[o] + bout[o]; m = fmaxf(m, v[o]); }
    float s = 0.f;
    #pragma unroll
    for (int o = 0; o < 5; ++o) s += __expf(v[o] - m);
    float l = logf(s) + m;
    #pragma unroll
    for (int o = 0; o < 5; ++o) out[b * 5 + o] = v[o] - l;
  }
}

// ---------------- launch ----------------
extern "C" void kernel_launch(void* const* d_in, const int* in_sizes, int n_in,
                              void* d_out, int out_size, void* d_ws, size_t ws_size,
                              hipStream_t stream) {
  const float* x      = (const float*)d_in[0];
  const int*   length = (const int*)d_in[1];
  const float* b_d    = (const float*)d_in[2];
  const float* W_mih  = (const float*)d_in[3];
  const float* W_mhh  = (const float*)d_in[4];
  const float* b_mih  = (const float*)d_in[5];
  const float* b_mhh  = (const float*)d_in[6];
  const float* W_ih   = (const float*)d_in[7];
  const float* W_hh   = (const float*)d_in[8];
  const float* b_ih   = (const float*)d_in[9];
  const float* b_hh   = (const float*)d_in[10];
  const float* W_out  = (const float*)d_in[11];
  const float* b_out  = (const float*)d_in[12];
  float* out = (float*)d_out;

  char* ws = (char*)d_ws;
  size_t off = 0;
  auto take = [&](size_t bytes) -> char* {
    char* p = ws + off;
    off += (bytes + 255) & ~(size_t)255;
    return p;
  };

  unsigned short* Xb     = (unsigned short*)take((size_t)T_STEPS * BATCH * IDIM * 2);
  unsigned short* Wmih_b = (unsigned short*)take(1536 * 512 * 2);
  unsigned short* Wmhh_b = (unsigned short*)take(1536 * 512 * 2);
  unsigned short* W2_b   = (unsigned short*)take(2048 * 1024 * 2);
  float* bA  = (float*)take(1536 * 4);
  float* bB  = (float*)take(2048 * 4);
  float* wd2 = (float*)take(KHIST * HDIM * 4);
  unsigned short* ring  = (unsigned short*)take((size_t)D_RING * BATCH * 512 * 2);
  unsigned short* h2buf = (unsigned short*)take((size_t)2 * BATCH * 512 * 2);
  float* sel = (float*)take((size_t)BATCH * HDIM * 4);
  int* counters = (int*)take(8192);           // aFlags at bs*64 ints, bFlags at 1024+bs*64 ints
  float* GX = (float*)take((size_t)T_STEPS * BATCH * 1536 * 4);
  if (off > ws_size) return;  // workspace too small -> loud validation failure

  hipMemsetAsync(counters, 0, 8192, stream);
  prep_misc_kernel<<<1, 1024, 0, stream>>>(b_d, b_mih, b_mhh, b_ih, b_hh, wd2, bA, bB);
  cast4_kernel<<<(T_STEPS * BATCH * IDIM / 4 + 255) / 256, 256, 0, stream>>>(x, Xb, T_STEPS * BATCH * IDIM / 4);
  cast4_kernel<<<(1536 * 512 / 4 + 255) / 256, 256, 0, stream>>>(W_mih, Wmih_b, 1536 * 512 / 4);
  cast4_kernel<<<(1536 * 512 / 4 + 255) / 256, 256, 0, stream>>>(W_mhh, Wmhh_b, 1536 * 512 / 4);
  pack_w2_kernel<<<(2048 * 1024 / 4 + 255) / 256, 256, 0, stream>>>(W_ih, W_hh, W2_b);
  gx_gemm_kernel<<<dim3(1536 / 64, T_STEPS * BATCH / 64), 256, 0, stream>>>(Xb, Wmih_b, bA, GX);

  hipFuncSetAttribute((const void*)recurrent2, hipFuncAttributeMaxDynamicSharedMemorySize, LDS_BYTES);
  void* kargs[] = { (void*)&GX, (void*)&Wmhh_b, (void*)&W2_b, (void*)&bB, (void*)&wd2,
                    (void*)&ring, (void*)&h2buf, (void*)&sel, (void*)&length,
                    (void*)&counters };
  hipLaunchCooperativeKernel((void*)recurrent2, dim3(256), dim3(512), kargs, LDS_BYTES, stream);

  out_head_kernel<<<BATCH, 64, 0, stream>>>(sel, W_out, b_out, out);
}

// Round 6
// 1652.434 us; speedup vs baseline: 6.5233x; 1.3952x over previous
//
#include <hip/hip_runtime.h>
#include <hip/hip_cooperative_groups.h>
#include <cstdint>
#include <cstddef>

typedef __attribute__((ext_vector_type(8))) short short8;   // 8 bf16 (4 VGPRs) MFMA frag
typedef __attribute__((ext_vector_type(4))) float floatx4;  // MFMA accumulator

#define T_STEPS 128
#define BATCH   256
#define IDIM    512
#define HDIM    512
#define KHIST   32
#define D_RING  4

// LDS layout sizes
#define WA_STRIDE 520      // 512 + 8 pad (bank spread)
#define WB_STRIDE 1032     // 1024 + 8 pad
#define LDS_BYTES 148480   // max(WB 64*1032*2 + EX 16384, WA 48*520*2 + HIST 65536)

__device__ __forceinline__ unsigned short f2bf(float x) {
  union { float f; unsigned u; } v; v.f = x;
  unsigned r = v.u + 0x7fffu + ((v.u >> 16) & 1u);   // RNE
  return (unsigned short)(r >> 16);
}
__device__ __forceinline__ float bf2f(unsigned short s) {
  union { unsigned u; float f; } v; v.u = ((unsigned)s) << 16; return v.f;
}
__device__ __forceinline__ float sigm(float x) { return 1.0f / (1.0f + __expf(-x)); }
__device__ __forceinline__ float tanh_f(float x) {
  float ax = fabsf(x);
  float e = __expf(-2.0f * ax);
  float t = (1.0f - e) / (1.0f + e);
  return x < 0.0f ? -t : t;
}

// ---- LLC-coherent (L1/L2-bypass) access helpers: sc0 sc1 ops never leave
// stale or dirty lines in any per-XCD L2, so NO buffer_inv / buffer_wbl2
// fences are needed in the steady-state handshake. ----

// Load a lane's 16 MFMA A-fragments (16B each, 64B stride) from LLC; one wait.
// NOTE: outputs MUST be early-clobber ("=&v") — the loads complete out of
// order w.r.t. the asm block, so no output may alias the address pair.
__device__ __forceinline__ void llc_load_1k(const unsigned short* p, short8* r) {
  asm volatile(
    "global_load_dwordx4 %0,  %16, off sc0 sc1\n\t"
    "global_load_dwordx4 %1,  %16, off offset:64 sc0 sc1\n\t"
    "global_load_dwordx4 %2,  %16, off offset:128 sc0 sc1\n\t"
    "global_load_dwordx4 %3,  %16, off offset:192 sc0 sc1\n\t"
    "global_load_dwordx4 %4,  %16, off offset:256 sc0 sc1\n\t"
    "global_load_dwordx4 %5,  %16, off offset:320 sc0 sc1\n\t"
    "global_load_dwordx4 %6,  %16, off offset:384 sc0 sc1\n\t"
    "global_load_dwordx4 %7,  %16, off offset:448 sc0 sc1\n\t"
    "global_load_dwordx4 %8,  %16, off offset:512 sc0 sc1\n\t"
    "global_load_dwordx4 %9,  %16, off offset:576 sc0 sc1\n\t"
    "global_load_dwordx4 %10, %16, off offset:640 sc0 sc1\n\t"
    "global_load_dwordx4 %11, %16, off offset:704 sc0 sc1\n\t"
    "global_load_dwordx4 %12, %16, off offset:768 sc0 sc1\n\t"
    "global_load_dwordx4 %13, %16, off offset:832 sc0 sc1\n\t"
    "global_load_dwordx4 %14, %16, off offset:896 sc0 sc1\n\t"
    "global_load_dwordx4 %15, %16, off offset:960 sc0 sc1\n\t"
    "s_waitcnt vmcnt(0)"
    : "=&v"(r[0]), "=&v"(r[1]), "=&v"(r[2]), "=&v"(r[3]),
      "=&v"(r[4]), "=&v"(r[5]), "=&v"(r[6]), "=&v"(r[7]),
      "=&v"(r[8]), "=&v"(r[9]), "=&v"(r[10]), "=&v"(r[11]),
      "=&v"(r[12]), "=&v"(r[13]), "=&v"(r[14]), "=&v"(r[15])
    : "v"(p)
    : "memory");
}

// Store 4 bf16 values to 4 consecutive rows (1024B stride) at one column.
__device__ __forceinline__ void llc_store_4rows(unsigned short* p,
                                                unsigned short a, unsigned short b,
                                                unsigned short c, unsigned short d) {
  asm volatile(
    "global_store_short %4, %0, off sc0 sc1\n\t"
    "global_store_short %4, %1, off offset:1024 sc0 sc1\n\t"
    "global_store_short %4, %2, off offset:2048 sc0 sc1\n\t"
    "global_store_short %4, %3, off offset:3072 sc0 sc1"
    :: "v"((unsigned)a), "v"((unsigned)b), "v"((unsigned)c), "v"((unsigned)d), "v"(p)
    : "memory");
}

__device__ __forceinline__ void drain_vm() {
  asm volatile("s_waitcnt vmcnt(0)" ::: "memory");
}

// ---------------- prep kernels ----------------

__global__ void cast4_kernel(const float* __restrict__ src, unsigned short* __restrict__ dst, int n4) {
  int i = blockIdx.x * blockDim.x + threadIdx.x;
  if (i >= n4) return;
  float4 v = reinterpret_cast<const float4*>(src)[i];
  ushort4 o;
  o.x = f2bf(v.x); o.y = f2bf(v.y); o.z = f2bf(v.z); o.w = f2bf(v.w);
  reinterpret_cast<ushort4*>(dst)[i] = o;
}

__global__ void pack_w2_kernel(const float* __restrict__ Wih, const float* __restrict__ Whh,
                               unsigned short* __restrict__ W2) {
  int i4 = blockIdx.x * blockDim.x + threadIdx.x;   // over 2048*1024/4
  if (i4 >= (2048 * 1024 / 4)) return;
  int i = i4 * 4; int n = i >> 10; int k = i & 1023;
  float4 v = (k < 512) ? reinterpret_cast<const float4*>(Wih + n * 512 + k)[0]
                       : reinterpret_cast<const float4*>(Whh + n * 512 + (k - 512))[0];
  ushort4 o;
  o.x = f2bf(v.x); o.y = f2bf(v.y); o.z = f2bf(v.z); o.w = f2bf(v.w);
  reinterpret_cast<ushort4*>(W2 + i)[0] = o;
}

__global__ void prep_misc_kernel(const float* __restrict__ b_d,
                                 const float* __restrict__ b_mih, const float* __restrict__ b_mhh,
                                 const float* __restrict__ b_ih,  const float* __restrict__ b_hh,
                                 float* __restrict__ wd2, float* __restrict__ bA, float* __restrict__ bB) {
  int tid = threadIdx.x;  // 1024 threads, 1 block
  if (tid < HDIM) {
    float d = 0.5f * sigm(b_d[tid]);
    float c = 1.0f;
    for (int i = 0; i < KHIST; ++i) {
      c *= ((float)i - d) / ((float)i + 1.0f);
      wd2[i * HDIM + tid] = c;          // wd2[j-1] = c_j
    }
  }
  for (int n = tid; n < 3 * HDIM; n += 1024) bA[n] = b_mih[n] + b_mhh[n];
  for (int n = tid; n < 4 * HDIM; n += 1024) bB[n] = b_ih[n] + b_hh[n];
}

// ---------------- big input-projection GEMM (fp32 out) ----------------
__global__ __launch_bounds__(256) void gx_gemm_kernel(const unsigned short* __restrict__ Xb,
                                                      const unsigned short* __restrict__ Wb,
                                                      const float* __restrict__ bA,
                                                      float* __restrict__ GX) {
  const int lane = threadIdx.x & 63;
  const int wave = threadIdx.x >> 6;
  const int q = lane >> 4, r16 = lane & 15;
  const int m0 = blockIdx.y * 64 + wave * 16;
  const int n0 = blockIdx.x * 64;
  floatx4 acc[4];
  #pragma unroll
  for (int i = 0; i < 4; ++i) acc[i] = (floatx4){0.f, 0.f, 0.f, 0.f};
  const unsigned short* arow = Xb + (size_t)(m0 + r16) * IDIM;
  #pragma unroll 4
  for (int k0 = 0; k0 < IDIM; k0 += 32) {
    short8 a = *(const short8*)(arow + k0 + q * 8);
    #pragma unroll
    for (int nt = 0; nt < 4; ++nt) {
      short8 b = *(const short8*)(Wb + (size_t)(n0 + nt * 16 + r16) * IDIM + k0 + q * 8);
      acc[nt] = __builtin_amdgcn_mfma_f32_16x16x32_bf16(a, b, acc[nt], 0, 0, 0);
    }
  }
  #pragma unroll
  for (int nt = 0; nt < 4; ++nt) {
    int col = n0 + nt * 16 + r16;
    float bias = bA[col];
    #pragma unroll
    for (int j = 0; j < 4; ++j) {
      int row = m0 + q * 4 + j;
      GX[(size_t)row * 1536 + col] = acc[nt][j] + bias;
    }
  }
}

// ---------------- async persistent recurrent kernel ----------------
// 256 blocks, XCD-swizzled: xcd = blk&7, slot = blk>>3.
//   group bs = xcd>>1; role A if xcd even, B if odd; hs = slot (32 h-slices).
// Handshake (fence-free): shared data (ring/h2buf) moves ONLY through sc0sc1
// LLC ops; producers drain vmcnt then store a per-block flag (relaxed agent
// atomic -> sc1); consumers poll 32 flags (1 lane each, relaxed). No
// buffer_inv / buffer_wbl2 anywhere in the steady-state loop.
__global__ __launch_bounds__(512, 1) void recurrent2(
    const float* __restrict__ GX,              // (T*256 x 1536) fp32
    const unsigned short* __restrict__ Wmhh,   // (1536 x 512) bf16 N-major
    const unsigned short* __restrict__ W2,     // (2048 x 1024) bf16 N-major
    const float* __restrict__ bB,              // (2048)
    const float* __restrict__ wd2,             // (32 x 512)
    unsigned short* __restrict__ ring,         // (4 x 256 x 512) bf16 h1n ring
    unsigned short* __restrict__ h2buf,        // (2 x 256 x 512) bf16
    float* __restrict__ sel,                   // (256 x 512) fp32
    const int* __restrict__ length,
    int* __restrict__ counters) {              // aFlags at bs*64, bFlags at 1024+bs*64
  extern __shared__ char lds[];
  const int tid = threadIdx.x;
  const int lane = tid & 63;
  const int wv = tid >> 6;                 // 0..7
  const int q = lane >> 4, r16 = lane & 15;
  const int xcd = (int)blockIdx.x & 7;
  const int slot = (int)blockIdx.x >> 3;
  const int bs = xcd >> 1;
  const bool isA = (xcd & 1) == 0;
  const int hs = slot;
  const int hcol = hs * 16 + r16;
  int* aFlags = counters + bs * 64;            // 32 ints used, 256B group spacing
  int* bFlags = counters + 1024 + bs * 64;

  if (isA) {
    unsigned short* WA = (unsigned short*)lds;                        // [48][520]
    unsigned short* HI = (unsigned short*)(lds + 48 * WA_STRIDE * 2); // hist [32][16 rg][16 c][4 j] bf16
    for (int idx = tid; idx < 48 * 64; idx += 512) {
      int rowi = idx >> 6, kc = idx & 63;
      int g = rowi >> 4, c = rowi & 15;
      const unsigned short* src = Wmhh + ((size_t)(g * 512 + hs * 16 + c)) * 512 + kc * 8;
      *(short8*)(WA + rowi * WA_STRIDE + kc * 8) = *(const short8*)src;
    }
    for (int idx = tid; idx < 4096; idx += 512)        // zero hist (64KB)
      ((uint4*)HI)[idx] = (uint4){0, 0, 0, 0};
    float wdr[KHIST];
    #pragma unroll
    for (int l = 0; l < KHIST; ++l) wdr[l] = wd2[l * HDIM + hcol];
    __syncthreads();

    const int mi = wv & 3;
    const int m0 = bs * 64 + mi * 16;
    const int rg = mi * 4 + q;            // row-group within block (rows rg*4+j)

    for (int s = 0; s < T_STEPS; ++s) {
      // prefetch GX for this step into registers BEFORE the wait (plain cached
      // loads; L2 is never invalidated now, so these increasingly hit L2)
      float gx0[4], gx1[4], gx2[4];
      if (wv < 4) {
        #pragma unroll
        for (int j = 0; j < 4; ++j) {
          int row = m0 + q * 4 + j;
          size_t gidx = ((size_t)s * BATCH + row) * 1536 + hcol;
          gx0[j] = GX[gidx];
          gx1[j] = GX[gidx + 512];
          gx2[j] = GX[gidx + 1024];
        }
      }
      if (wv == 0) {
        const int* f; int tgt;
        if (lane < 32) { f = aFlags + lane; tgt = s; }                 // peers done s-1
        else           { f = bFlags + (lane - 32); tgt = s - (D_RING - 1); }  // ring slot free
        if (tgt > 0)
          while (__hip_atomic_load(f, __ATOMIC_RELAXED, __HIP_MEMORY_SCOPE_AGENT) < tgt)
            __builtin_amdgcn_s_sleep(2);
      }
      __syncthreads();
      if (wv < 4) {
        floatx4 acc[3];
        #pragma unroll
        for (int g = 0; g < 3; ++g) acc[g] = (floatx4){0.f, 0.f, 0.f, 0.f};
        if (s > 0) {
          const unsigned short* abase =
              ring + ((size_t)((s - 1) & 3) * BATCH + m0 + r16) * 512 + q * 8;
          short8 af[16];
          llc_load_1k(abase, af);
          #pragma unroll
          for (int kk = 0; kk < 16; ++kk) {
            #pragma unroll
            for (int g = 0; g < 3; ++g) {
              short8 b = *(const short8*)(WA + (size_t)(g * 16 + r16) * WA_STRIDE + kk * 32 + q * 8);
              acc[g] = __builtin_amdgcn_mfma_f32_16x16x32_bf16(af[kk], b, acc[g], 0, 0, 0);
            }
          }
        }
        // frac-diff filter from LDS hist
        float f0 = 0.f, f1 = 0.f, f2 = 0.f, f3 = 0.f;
        #pragma unroll
        for (int jj = 1; jj <= KHIST; ++jj) {
          int sl = (s - jj) & (KHIST - 1);
          ushort4 hv = *(const ushort4*)(HI + ((size_t)(sl * 16 + rg) * 16 + r16) * 4);
          float wc = wdr[jj - 1];
          f0 += wc * bf2f(hv.x); f1 += wc * bf2f(hv.y);
          f2 += wc * bf2f(hv.z); f3 += wc * bf2f(hv.w);
        }
        float fj[4] = {f0, f1, f2, f3};
        float c1[4];
        unsigned short h1w[4];
        #pragma unroll
        for (int j = 0; j < 4; ++j) {
          float gI = gx0[j] + acc[0][j];
          float gO = gx1[j] + acc[1][j];
          float gG = gx2[j] + acc[2][j];
          float ig = sigm(gI), og = sigm(gO), cd = tanh_f(gG);
          float c1v = ig * cd - fj[j];
          c1[j] = c1v;
          h1w[j] = f2bf(og * tanh_f(c1v));
        }
        llc_store_4rows(ring + ((size_t)(s & 3) * BATCH + m0 + q * 4) * 512 + hcol,
                        h1w[0], h1w[1], h1w[2], h1w[3]);
        ushort4 hw;
        hw.x = f2bf(c1[0]); hw.y = f2bf(c1[1]); hw.z = f2bf(c1[2]); hw.w = f2bf(c1[3]);
        *(ushort4*)(HI + ((size_t)((s & (KHIST - 1)) * 16 + rg) * 16 + r16) * 4) = hw;
      }
      drain_vm();        // each wave: ring stores acked at LLC before barrier
      __syncthreads();
      if (tid == 0)
        __hip_atomic_store(aFlags + hs, s + 1, __ATOMIC_RELAXED, __HIP_MEMORY_SCOPE_AGENT);
    }
  } else {
    // ---- B block ----
    unsigned short* WB = (unsigned short*)lds;                 // [64][1032]
    float* EX = (float*)(lds + 64 * WB_STRIDE * 2);            // exch [4 mi][4 g][64 lane][4]
    for (int idx = tid; idx < 64 * 128; idx += 512) {
      int rowi = idx >> 7, kc = idx & 127;
      int g = rowi >> 4, c = rowi & 15;
      const unsigned short* src = W2 + ((size_t)(g * 512 + hs * 16 + c)) * 1024 + kc * 8;
      *(short8*)(WB + rowi * WB_STRIDE + kc * 8) = *(const short8*)src;
    }
    const int mi = wv >> 1, kh = wv & 1;
    const int m0 = bs * 64 + mi * 16;
    float c2r[4] = {0.f, 0.f, 0.f, 0.f};
    int lenr[4];
    float bBr[4];
    #pragma unroll
    for (int j = 0; j < 4; ++j) lenr[j] = length[m0 + q * 4 + j];
    #pragma unroll
    for (int g = 0; g < 4; ++g) bBr[g] = bB[g * 512 + hcol];
    __syncthreads();

    for (int t = 0; t < T_STEPS; ++t) {
      if (wv == 0) {
        const int* f; int tgt;
        if (lane < 32) { f = aFlags + lane; tgt = t + 1; }             // A done t
        else           { f = bFlags + (lane - 32); tgt = t; }          // B peers done t-1
        if (tgt > 0)
          while (__hip_atomic_load(f, __ATOMIC_RELAXED, __HIP_MEMORY_SCOPE_AGENT) < tgt)
            __builtin_amdgcn_s_sleep(2);
      }
      __syncthreads();
      floatx4 acc[4];
      #pragma unroll
      for (int g = 0; g < 4; ++g) acc[g] = (floatx4){0.f, 0.f, 0.f, 0.f};
      bool doit = true;
      const unsigned short* abase;
      if (kh == 0) {
        abase = ring + ((size_t)(t & 3) * BATCH + m0 + r16) * 512 + q * 8;
      } else {
        if (t == 0) doit = false;
        abase = h2buf + ((size_t)((t - 1) & 1) * BATCH + m0 + r16) * 512 + q * 8;
      }
      if (doit) {
        short8 af[16];
        llc_load_1k(abase, af);
        #pragma unroll
        for (int kk = 0; kk < 16; ++kk) {
          #pragma unroll
          for (int g = 0; g < 4; ++g) {
            short8 b = *(const short8*)(WB + (size_t)(g * 16 + r16) * WB_STRIDE + kh * 512 + kk * 32 + q * 8);
            acc[g] = __builtin_amdgcn_mfma_f32_16x16x32_bf16(af[kk], b, acc[g], 0, 0, 0);
          }
        }
      }
      if (kh == 1) {
        #pragma unroll
        for (int g = 0; g < 4; ++g)
          *(floatx4*)(EX + ((size_t)(mi * 4 + g) * 64 + lane) * 4) = acc[g];
      }
      __syncthreads();
      if (kh == 0) {
        #pragma unroll
        for (int g = 0; g < 4; ++g)
          acc[g] += *(const floatx4*)(EX + ((size_t)(mi * 4 + g) * 64 + lane) * 4);
        unsigned short h2w[4];
        #pragma unroll
        for (int j = 0; j < 4; ++j) {
          int row = m0 + q * 4 + j;
          float gi = acc[0][j] + bBr[0];
          float gf = acc[1][j] + bBr[1];
          float gg = acc[2][j] + bBr[2];
          float go = acc[3][j] + bBr[3];
          float c2n = sigm(gf) * c2r[j] + sigm(gi) * tanh_f(gg);
          c2r[j] = c2n;
          float h2n = tanh_f(sigm(go) * tanh_f(c2n));
          h2w[j] = f2bf(h2n);
          if (lenr[j] == t) sel[(size_t)row * 512 + hcol] = h2n;
        }
        llc_store_4rows(h2buf + ((size_t)(t & 1) * BATCH + m0 + q * 4) * 512 + hcol,
                        h2w[0], h2w[1], h2w[2], h2w[3]);
      }
      drain_vm();
      __syncthreads();
      if (tid == 0)
        __hip_atomic_store(bFlags + hs, t + 1, __ATOMIC_RELAXED, __HIP_MEMORY_SCOPE_AGENT);
    }
  }
}

// ---------------- output head ----------------
__global__ void out_head_kernel(const float* __restrict__ sel, const float* __restrict__ Wout,
                                const float* __restrict__ bout, float* __restrict__ out) {
  int b = blockIdx.x, lane = threadIdx.x;   // 256 blocks x 64 threads
  float acc[5] = {0.f, 0.f, 0.f, 0.f, 0.f};
  for (int j = lane; j < HDIM; j += 64) {
    float x = sel[(size_t)b * HDIM + j];
    #pragma unroll
    for (int o = 0; o < 5; ++o) acc[o] += x * Wout[o * HDIM + j];
  }
  #pragma unroll
  for (int o = 0; o < 5; ++o)
    for (int off = 32; off > 0; off >>= 1) acc[o] += __shfl_down(acc[o], off);
  if (lane == 0) {
    float v[5]; float m = -1e30f;
    #pragma unroll
    for (int o = 0; o < 5; ++o) { v[o] = acc[o] + bout[o]; m = fmaxf(m, v[o]); }
    float s = 0.f;
    #pragma unroll
    for (int o = 0; o < 5; ++o) s += __expf(v[o] - m);
    float l = logf(s) + m;
    #pragma unroll
    for (int o = 0; o < 5; ++o) out[b * 5 + o] = v[o] - l;
  }
}

// ---------------- launch ----------------
extern "C" void kernel_launch(void* const* d_in, const int* in_sizes, int n_in,
                              void* d_out, int out_size, void* d_ws, size_t ws_size,
                              hipStream_t stream) {
  const float* x      = (const float*)d_in[0];
  const int*   length = (const int*)d_in[1];
  const float* b_d    = (const float*)d_in[2];
  const float* W_mih  = (const float*)d_in[3];
  const float* W_mhh  = (const float*)d_in[4];
  const float* b_mih  = (const float*)d_in[5];
  const float* b_mhh  = (const float*)d_in[6];
  const float* W_ih   = (const float*)d_in[7];
  const float* W_hh   = (const float*)d_in[8];
  const float* b_ih   = (const float*)d_in[9];
  const float* b_hh   = (const float*)d_in[10];
  const float* W_out  = (const float*)d_in[11];
  const float* b_out  = (const float*)d_in[12];
  float* out = (float*)d_out;

  char* ws = (char*)d_ws;
  size_t off = 0;
  auto take = [&](size_t bytes) -> char* {
    char* p = ws + off;
    off += (bytes + 255) & ~(size_t)255;
    return p;
  };

  unsigned short* Xb     = (unsigned short*)take((size_t)T_STEPS * BATCH * IDIM * 2);
  unsigned short* Wmih_b = (unsigned short*)take(1536 * 512 * 2);
  unsigned short* Wmhh_b = (unsigned short*)take(1536 * 512 * 2);
  unsigned short* W2_b   = (unsigned short*)take(2048 * 1024 * 2);
  float* bA  = (float*)take(1536 * 4);
  float* bB  = (float*)take(2048 * 4);
  float* wd2 = (float*)take(KHIST * HDIM * 4);
  unsigned short* ring  = (unsigned short*)take((size_t)D_RING * BATCH * 512 * 2);
  unsigned short* h2buf = (unsigned short*)take((size_t)2 * BATCH * 512 * 2);
  float* sel = (float*)take((size_t)BATCH * HDIM * 4);
  int* counters = (int*)take(8192);           // aFlags at bs*64 ints, bFlags at 1024+bs*64 ints
  float* GX = (float*)take((size_t)T_STEPS * BATCH * 1536 * 4);
  if (off > ws_size) return;  // workspace too small -> loud validation failure

  hipMemsetAsync(counters, 0, 8192, stream);
  prep_misc_kernel<<<1, 1024, 0, stream>>>(b_d, b_mih, b_mhh, b_ih, b_hh, wd2, bA, bB);
  cast4_kernel<<<(T_STEPS * BATCH * IDIM / 4 + 255) / 256, 256, 0, stream>>>(x, Xb, T_STEPS * BATCH * IDIM / 4);
  cast4_kernel<<<(1536 * 512 / 4 + 255) / 256, 256, 0, stream>>>(W_mih, Wmih_b, 1536 * 512 / 4);
  cast4_kernel<<<(1536 * 512 / 4 + 255) / 256, 256, 0, stream>>>(W_mhh, Wmhh_b, 1536 * 512 / 4);
  pack_w2_kernel<<<(2048 * 1024 / 4 + 255) / 256, 256, 0, stream>>>(W_ih, W_hh, W2_b);
  gx_gemm_kernel<<<dim3(1536 / 64, T_STEPS * BATCH / 64), 256, 0, stream>>>(Xb, Wmih_b, bA, GX);

  hipFuncSetAttribute((const void*)recurrent2, hipFuncAttributeMaxDynamicSharedMemorySize, LDS_BYTES);
  void* kargs[] = { (void*)&GX, (void*)&Wmhh_b, (void*)&W2_b, (void*)&bB, (void*)&wd2,
                    (void*)&ring, (void*)&h2buf, (void*)&sel, (void*)&length,
                    (void*)&counters };
  hipLaunchCooperativeKernel((void*)recurrent2, dim3(256), dim3(512), kargs, LDS_BYTES, stream);

  out_head_kernel<<<BATCH, 64, 0, stream>>>(sel, W_out, b_out, out);
}